// Round 6
// baseline (669.719 us; speedup 1.0000x reference)
//
#include <hip/hip_runtime.h>

#define BB 4
#define NN 4096
#define DD 256
#define PP 64
#define HH 1024
#define NCC 256
#define TOPK 8

// ---------------------------------------------------------------------------
// K1: Q = A@Wq+bq, K = A@Wk+bk, proj = A@Wc+bc, pn = proj/max(||proj||,1e-12)
// ---------------------------------------------------------------------------
__global__ __launch_bounds__(256) void k_proj(
    const float* __restrict__ act,
    const float* __restrict__ Wq, const float* __restrict__ bq,
    const float* __restrict__ Wk, const float* __restrict__ bk,
    const float* __restrict__ Wc, const float* __restrict__ bc,
    float* __restrict__ Qo, float* __restrict__ Ko, float* __restrict__ PNo)
{
    __shared__ float As[16][DD];   // 16KB
    __shared__ float Ps[16][PP];   // 4KB
    const int tid = threadIdx.x;
    const long row0 = (long)blockIdx.x * 16;

    {
        const float4* g4 = (const float4*)(act + row0 * DD);
        float4* s4 = (float4*)(&As[0][0]);
#pragma unroll
        for (int i = 0; i < 4; ++i) s4[tid + i * 256] = g4[tid + i * 256];
    }
    __syncthreads();

    const int col = tid & 63;
    const int rg  = tid >> 6;   // 0..3 -> rows rg*4+j
    float aq[4], ak[4], ac[4];
#pragma unroll
    for (int j = 0; j < 4; ++j) { aq[j] = bq[col]; ak[j] = bk[col]; ac[j] = bc[col]; }

    for (int d = 0; d < DD; ++d) {
        float wq = Wq[d * PP + col];
        float wk = Wk[d * PP + col];
        float wc = Wc[d * PP + col];
#pragma unroll
        for (int j = 0; j < 4; ++j) {
            float a = As[rg * 4 + j][d];
            aq[j] = fmaf(a, wq, aq[j]);
            ak[j] = fmaf(a, wk, ak[j]);
            ac[j] = fmaf(a, wc, ac[j]);
        }
    }
#pragma unroll
    for (int j = 0; j < 4; ++j) {
        long r = row0 + rg * 4 + j;
        Qo[r * PP + col] = aq[j];
        Ko[r * PP + col] = ak[j];
        Ps[rg * 4 + j][col] = ac[j];
    }
    __syncthreads();

    const int w = tid >> 6;
    const int lane = tid & 63;
#pragma unroll
    for (int j = 0; j < 4; ++j) {
        int r = w * 4 + j;
        float v = Ps[r][lane];
        float ss = v * v;
#pragma unroll
        for (int off = 32; off >= 1; off >>= 1) ss += __shfl_xor(ss, off, 64);
        float nrm = fmaxf(sqrtf(ss), 1e-12f);
        PNo[(row0 + r) * PP + lane] = v / nrm;
    }
}

// ---------------------------------------------------------------------------
// K2: scores = Q K^T -> per-row top-8 -> softmax -> incoming gather.
// 16 rows/block (grid = BB*256 = 1024 -> 4 blocks/CU), 36KB LDS,
// topv/topi[2][8] keeps live set ~95 regs (no spill at the 128 cap).
// ---------------------------------------------------------------------------
__global__ __launch_bounds__(256, 4) void k_topk(
    const float* __restrict__ Q, const float* __restrict__ K,
    const float* __restrict__ states, float* __restrict__ incoming)
{
    __shared__ float Qs[16][PP];       // 4KB
    __shared__ float4 Ks4[128 * 16];   // 32KB, XOR-swizzled float4 slots

    const int tid = threadIdx.x;
    const int b  = blockIdx.x >> 8;          // grid = BB * 256
    const int n0 = (blockIdx.x & 255) << 4;  // 16 rows/block

    {
        const float4* g4 = (const float4*)(Q + ((long)b * NN + n0) * PP);
        ((float4*)(&Qs[0][0]))[tid] = g4[tid];
    }

    const int mg = tid & 31;        // m sub-index (lane within half-wave)
    const int rg = tid >> 5;        // 0..7 -> rows rg+8j, j in {0,1}
    const int m15 = mg & 15;
    // sorted descending: topv[j][0] >= ... >= topv[j][7]
    float topv[2][TOPK];
    int   topi[2][TOPK];
#pragma unroll
    for (int j = 0; j < 2; ++j)
#pragma unroll
        for (int t = 0; t < TOPK; ++t) { topv[j][t] = -1e30f; topi[j][t] = 0; }

    for (int mt = 0; mt < NN / 128; ++mt) {
        const int m0 = mt << 7;
        __syncthreads();
        {
            const float4* g4 = (const float4*)(K + ((long)b * NN + m0) * PP);
#pragma unroll
            for (int t = 0; t < 8; ++t) {
                int q = tid + t * 256;                 // 0..2047 float4s
                int row = q >> 4, sl = q & 15;
                Ks4[(row << 4) | (sl ^ (row & 15))] = g4[q];
            }
        }
        __syncthreads();

        float s[2][4];
#pragma unroll
        for (int j = 0; j < 2; ++j)
#pragma unroll
            for (int k = 0; k < 4; ++k) s[j][k] = 0.f;

#pragma unroll 4
        for (int sl = 0; sl < 16; ++sl) {              // p = 4*sl
            const int sw = sl ^ m15;
            float4 qv[2], kv[4];
#pragma unroll
            for (int j = 0; j < 2; ++j) qv[j] = *(const float4*)(&Qs[rg + 8 * j][sl << 2]);
#pragma unroll
            for (int k = 0; k < 4; ++k) kv[k] = Ks4[((mg + 32 * k) << 4) + sw];
#pragma unroll
            for (int j = 0; j < 2; ++j)
#pragma unroll
                for (int k = 0; k < 4; ++k) {
                    s[j][k] = fmaf(qv[j].x, kv[k].x, s[j][k]);
                    s[j][k] = fmaf(qv[j].y, kv[k].y, s[j][k]);
                    s[j][k] = fmaf(qv[j].z, kv[k].z, s[j][k]);
                    s[j][k] = fmaf(qv[j].w, kv[k].w, s[j][k]);
                }
        }

        // branchless sorted-desc insert (equal vals keep earlier/lower idx above)
#pragma unroll
        for (int j = 0; j < 2; ++j) {
#pragma unroll
            for (int k = 0; k < 4; ++k) {
                float val = s[j][k];
                int idx = m0 + mg + 32 * k;
                if (val > topv[j][TOPK - 1]) {
                    bool c[TOPK];
#pragma unroll
                    for (int t = 0; t < TOPK; ++t) c[t] = (val > topv[j][t]);
#pragma unroll
                    for (int t = TOPK - 1; t >= 1; --t) {
                        topv[j][t] = c[t - 1] ? topv[j][t - 1] : (c[t] ? val : topv[j][t]);
                        topi[j][t] = c[t - 1] ? topi[j][t - 1] : (c[t] ? idx : topi[j][t]);
                    }
                    topv[j][0] = c[0] ? val : topv[j][0];
                    topi[j][0] = c[0] ? idx : topi[j][0];
                }
            }
        }
    }

    // ---- in-register merge within each half-wave (32 lanes share row rr) ----
#pragma unroll
    for (int j = 0; j < 2; ++j) {
        const int rr = rg + 8 * j;
        float wv[TOPK]; int wi[TOPK];
#pragma unroll
        for (int e = 0; e < TOPK; ++e) {
            float lv = topv[j][0]; int li = topi[j][0];
#pragma unroll
            for (int off = 16; off >= 1; off >>= 1) {
                float ov = __shfl_xor(lv, off, 64);
                int   oi = __shfl_xor(li, off, 64);
                bool tk = (ov > lv) || (ov == lv && oi < li);
                lv = tk ? ov : lv;
                li = tk ? oi : li;
            }
            wv[e] = lv; wi[e] = li;
            bool pop = (topv[j][0] == lv) && (topi[j][0] == li);
#pragma unroll
            for (int t = 0; t < TOPK - 1; ++t) {
                topv[j][t] = pop ? topv[j][t + 1] : topv[j][t];
                topi[j][t] = pop ? topi[j][t + 1] : topi[j][t];
            }
            topv[j][TOPK - 1] = pop ? -1e30f : topv[j][TOPK - 1];
            topi[j][TOPK - 1] = pop ? 0x7FFFFFFF : topi[j][TOPK - 1];
        }

        // softmax over the 8 (wv[0] is the max), then gather by half-wave
        float mx = wv[0] * 0.125f;
        float ex[TOPK]; float Z = 0.f;
#pragma unroll
        for (int e = 0; e < TOPK; ++e) { ex[e] = expf(wv[e] * 0.125f - mx); Z += ex[e]; }
        float invZ = 1.0f / Z;

        float4 a0 = {0.f, 0.f, 0.f, 0.f}, a1 = {0.f, 0.f, 0.f, 0.f};
#pragma unroll
        for (int e = 0; e < TOPK; ++e) {
            const float4* sp = (const float4*)(states + ((long)b * NN + wi[e]) * DD);
            float4 s0 = sp[mg];
            float4 s1 = sp[mg + 32];
            float we = ex[e] * invZ;
            a0.x = fmaf(we, s0.x, a0.x); a0.y = fmaf(we, s0.y, a0.y);
            a0.z = fmaf(we, s0.z, a0.z); a0.w = fmaf(we, s0.w, a0.w);
            a1.x = fmaf(we, s1.x, a1.x); a1.y = fmaf(we, s1.y, a1.y);
            a1.z = fmaf(we, s1.z, a1.z); a1.w = fmaf(we, s1.w, a1.w);
        }
        float4* op = (float4*)(incoming + ((long)b * NN + n0 + rr) * DD);
        op[mg] = a0;
        op[mg + 32] = a1;
    }
}

// ---------------------------------------------------------------------------
// K3: sim = pn pn^T; cmask = sim>0.7; combined; out = 0.8*inc + 0.2*combined
// 16 rows/block (grid 1024 -> 4 blocks/CU), ~38KB LDS.
// ---------------------------------------------------------------------------
#define CAP 64
__global__ __launch_bounds__(256, 4) void k_coal(
    const float* __restrict__ PN, const float* __restrict__ incoming,
    float* __restrict__ outs)
{
    __shared__ float Qs[16][PP];        // 4KB
    __shared__ float4 Ks4[128 * 16];    // 32KB, swizzled
    __shared__ int cnt[16];
    __shared__ unsigned short lst[16][CAP];   // 2KB

    const int tid = threadIdx.x;
    const int b  = blockIdx.x >> 8;
    const int n0 = (blockIdx.x & 255) << 4;

    if (tid < 16) cnt[tid] = 0;
    {
        const float4* g4 = (const float4*)(PN + ((long)b * NN + n0) * PP);
        ((float4*)(&Qs[0][0]))[tid] = g4[tid];
    }

    const int mg = tid & 31;
    const int rg = tid >> 5;
    const int m15 = mg & 15;

    for (int mt = 0; mt < NN / 128; ++mt) {
        const int m0 = mt << 7;
        __syncthreads();
        {
            const float4* g4 = (const float4*)(PN + ((long)b * NN + m0) * PP);
#pragma unroll
            for (int t = 0; t < 8; ++t) {
                int q = tid + t * 256;
                int row = q >> 4, sl = q & 15;
                Ks4[(row << 4) | (sl ^ (row & 15))] = g4[q];
            }
        }
        __syncthreads();

        float s[2][4];
#pragma unroll
        for (int j = 0; j < 2; ++j)
#pragma unroll
            for (int k = 0; k < 4; ++k) s[j][k] = 0.f;

#pragma unroll 4
        for (int sl = 0; sl < 16; ++sl) {
            const int sw = sl ^ m15;
            float4 qv[2], kv[4];
#pragma unroll
            for (int j = 0; j < 2; ++j) qv[j] = *(const float4*)(&Qs[rg + 8 * j][sl << 2]);
#pragma unroll
            for (int k = 0; k < 4; ++k) kv[k] = Ks4[((mg + 32 * k) << 4) + sw];
#pragma unroll
            for (int j = 0; j < 2; ++j)
#pragma unroll
                for (int k = 0; k < 4; ++k) {
                    s[j][k] = fmaf(qv[j].x, kv[k].x, s[j][k]);
                    s[j][k] = fmaf(qv[j].y, kv[k].y, s[j][k]);
                    s[j][k] = fmaf(qv[j].z, kv[k].z, s[j][k]);
                    s[j][k] = fmaf(qv[j].w, kv[k].w, s[j][k]);
                }
        }

#pragma unroll
        for (int j = 0; j < 2; ++j)
#pragma unroll
            for (int k = 0; k < 4; ++k) {
                if (s[j][k] > 0.7f) {
                    int pos = atomicAdd(&cnt[rg + 8 * j], 1);
                    if (pos < CAP) lst[rg + 8 * j][pos] = (unsigned short)(m0 + mg + 32 * k);
                }
            }
    }
    __syncthreads();

    // wave w handles rows w*4 .. w*4+3
    const int w = tid >> 6;
    const int lane = tid & 63;
    for (int rr = w * 4; rr < w * 4 + 4; ++rr) {
        int c = cnt[rr];
        float inv = 1.0f / ((float)c + 1e-8f);
        int cc = (c < CAP) ? c : CAP;
        float ax = 0.f, ay = 0.f, az = 0.f, aw = 0.f;
        for (int i = 0; i < cc; ++i) {
            const float4* ip = (const float4*)(incoming + ((long)b * NN + lst[rr][i]) * DD);
            float4 v = ip[lane];
            ax += v.x; ay += v.y; az += v.z; aw += v.w;
        }
        const float4* self4 = (const float4*)(incoming + ((long)b * NN + n0 + rr) * DD);
        float4 sv = self4[lane];
        float4 o;
        o.x = 0.8f * sv.x + 0.2f * inv * ax;
        o.y = 0.8f * sv.y + 0.2f * inv * ay;
        o.z = 0.8f * sv.z + 0.2f * inv * az;
        o.w = 0.8f * sv.w + 0.2f * inv * aw;
        ((float4*)(outs + ((long)b * NN + n0 + rr) * DD))[lane] = o;
    }
}

// ---------------------------------------------------------------------------
// K4: hdc = tanh(3(out@Wh+bh)); bind; decay-write; cosine read.
// 48KB LDS -> 3 blocks/CU with (256,3).
// ---------------------------------------------------------------------------
__global__ __launch_bounds__(256, 3) void k_mem(
    const float* __restrict__ outs, const float* __restrict__ Wh,
    const float* __restrict__ bh, const float* __restrict__ keys,
    const float* __restrict__ pos_codes, const int* __restrict__ stepp,
    const float* __restrict__ mem,
    float* __restrict__ epi_out, float* __restrict__ sim_out)
{
    __shared__ float Ss[16][DD];    // 16KB
    __shared__ float Wt[8][HH];     // 32KB
    __shared__ float red[4][8][3];

    const int tid = threadIdx.x;
    const long row0 = (long)blockIdx.x * 16;

    {
        const float4* g4 = (const float4*)(outs + row0 * DD);
        float4* s4 = (float4*)(&Ss[0][0]);
#pragma unroll
        for (int i = 0; i < 4; ++i) s4[tid + i * 256] = g4[tid + i * 256];
    }

    const int hg = tid & 127;       // h = hg + 128k
    const int rg = tid >> 7;        // rows rg*8+j
    float acc[8][8];
#pragma unroll
    for (int j = 0; j < 8; ++j)
#pragma unroll
        for (int k = 0; k < 8; ++k) acc[j][k] = 0.f;

    for (int dt = 0; dt < DD / 8; ++dt) {
        __syncthreads();
        {
            const float4* g4 = (const float4*)(Wh + (long)dt * 8 * HH);
            float4* s4 = (float4*)(&Wt[0][0]);
#pragma unroll
            for (int t = 0; t < 8; ++t) s4[tid + t * 256] = g4[tid + t * 256];
        }
        __syncthreads();
#pragma unroll
        for (int dq = 0; dq < 2; ++dq) {
            float sv[8][4];
#pragma unroll
            for (int j = 0; j < 8; ++j) {
                float4 t4 = *(const float4*)(&Ss[rg * 8 + j][dt * 8 + dq * 4]);
                sv[j][0] = t4.x; sv[j][1] = t4.y; sv[j][2] = t4.z; sv[j][3] = t4.w;
            }
#pragma unroll
            for (int d2 = 0; d2 < 4; ++d2) {
                float wvv[8];
#pragma unroll
                for (int k = 0; k < 8; ++k) wvv[k] = Wt[dq * 4 + d2][hg + 128 * k];
#pragma unroll
                for (int j = 0; j < 8; ++j)
#pragma unroll
                    for (int k = 0; k < 8; ++k)
                        acc[j][k] = fmaf(sv[j][d2], wvv[k], acc[j][k]);
            }
        }
    }

    const int step = stepp[0];
    const int prow = ((step % NCC) + NCC) % NCC;
    float dnp[8], dnn[8], dpp[8];
#pragma unroll
    for (int j = 0; j < 8; ++j) { dnp[j] = 0.f; dnn[j] = 0.f; dpp[j] = 0.f; }

#pragma unroll
    for (int k = 0; k < 8; ++k) {
        int h = hg + 128 * k;
        float ps = pos_codes[(long)prow * HH + h];
        float bb = bh[h];
#pragma unroll
        for (int j = 0; j < 8; ++j) {
            long row = row0 + rg * 8 + j;
            int n = (int)(row & (NN - 1));
            float y = acc[j][k] + bb;
            float hd = tanhf(3.0f * y);
            float per = hd * keys[(long)n * HH + h];
            float bound = per * ps;
            float ne = 0.95f * mem[row * HH + h] + 0.05f * bound;
            epi_out[row * HH + h] = ne;
            dnp[j] = fmaf(ne, per, dnp[j]);
            dnn[j] = fmaf(ne, ne, dnn[j]);
            dpp[j] = fmaf(per, per, dpp[j]);
        }
    }

#pragma unroll
    for (int j = 0; j < 8; ++j) {
#pragma unroll
        for (int off = 32; off >= 1; off >>= 1) {
            dnp[j] += __shfl_xor(dnp[j], off, 64);
            dnn[j] += __shfl_xor(dnn[j], off, 64);
            dpp[j] += __shfl_xor(dpp[j], off, 64);
        }
    }
    const int w = tid >> 6;
    const int lane = tid & 63;
    if (lane == 0) {
#pragma unroll
        for (int j = 0; j < 8; ++j) {
            red[w][j][0] = dnp[j]; red[w][j][1] = dnn[j]; red[w][j][2] = dpp[j];
        }
    }
    __syncthreads();
    if (tid < 16) {
        int rgp = tid >> 3, j = tid & 7;
        float dot = red[rgp * 2][j][0] + red[rgp * 2 + 1][j][0];
        float nn  = red[rgp * 2][j][1] + red[rgp * 2 + 1][j][1];
        float pp  = red[rgp * 2][j][2] + red[rgp * 2 + 1][j][2];
        float na = fmaxf(sqrtf(nn), 1e-8f);
        float nb = fmaxf(sqrtf(pp), 1e-8f);
        sim_out[row0 + rgp * 8 + j] = dot / (na * nb);
    }
}

// ---------------------------------------------------------------------------
extern "C" void kernel_launch(void* const* d_in, const int* in_sizes, int n_in,
                              void* d_out, int out_size, void* d_ws, size_t ws_size,
                              hipStream_t stream)
{
    const float* states  = (const float*)d_in[0];
    const float* actions = (const float*)d_in[1];
    const float* mem     = (const float*)d_in[2];
    const float* Wq = (const float*)d_in[3];
    const float* bq = (const float*)d_in[4];
    const float* Wk = (const float*)d_in[5];
    const float* bk = (const float*)d_in[6];
    const float* Wc = (const float*)d_in[7];
    const float* bc = (const float*)d_in[8];
    const float* Wh = (const float*)d_in[9];
    const float* bh = (const float*)d_in[10];
    const float* keys = (const float*)d_in[11];
    const float* pos  = (const float*)d_in[12];
    const int*   step = (const int*)d_in[13];

    float* ws = (float*)d_ws;
    float* Q        = ws;                    // 1,048,576 floats
    float* K        = ws + 1048576;          // 1,048,576
    float* PN       = ws + 2097152;          // 1,048,576
    float* incoming = ws + 3145728;          // 4,194,304

    float* outs = (float*)d_out;                       // B*N*D
    float* epi  = outs + (long)BB * NN * DD;           // B*N*H
    float* simo = epi + (long)BB * NN * HH;            // B*N

    hipLaunchKernelGGL(k_proj, dim3(BB * NN / 16), dim3(256), 0, stream,
                       actions, Wq, bq, Wk, bk, Wc, bc, Q, K, PN);
    hipLaunchKernelGGL(k_topk, dim3(BB * (NN / 16)), dim3(256), 0, stream,
                       Q, K, states, incoming);
    hipLaunchKernelGGL(k_coal, dim3(BB * (NN / 16)), dim3(256), 0, stream,
                       PN, incoming, outs);
    hipLaunchKernelGGL(k_mem, dim3(BB * NN / 16), dim3(256), 0, stream,
                       outs, Wh, bh, keys, pos, step, mem, epi, simo);
}

// Round 7
// 584.318 us; speedup vs baseline: 1.1462x; 1.1462x over previous
//
#include <hip/hip_runtime.h>

#define BB 4
#define NN 4096
#define DD 256
#define PP 64
#define HH 1024
#define NCC 256
#define TOPK 8

// ---------------------------------------------------------------------------
// K1: Q = A@Wq+bq, K = A@Wk+bk, proj = A@Wc+bc, pn = proj/max(||proj||,1e-12)
// ---------------------------------------------------------------------------
__global__ __launch_bounds__(256) void k_proj(
    const float* __restrict__ act,
    const float* __restrict__ Wq, const float* __restrict__ bq,
    const float* __restrict__ Wk, const float* __restrict__ bk,
    const float* __restrict__ Wc, const float* __restrict__ bc,
    float* __restrict__ Qo, float* __restrict__ Ko, float* __restrict__ PNo)
{
    __shared__ float As[16][DD];   // 16KB
    __shared__ float Ps[16][PP];   // 4KB
    const int tid = threadIdx.x;
    const long row0 = (long)blockIdx.x * 16;

    {
        const float4* g4 = (const float4*)(act + row0 * DD);
        float4* s4 = (float4*)(&As[0][0]);
#pragma unroll
        for (int i = 0; i < 4; ++i) s4[tid + i * 256] = g4[tid + i * 256];
    }
    __syncthreads();

    const int col = tid & 63;
    const int rg  = tid >> 6;   // 0..3 -> rows rg*4+j
    float aq[4], ak[4], ac[4];
#pragma unroll
    for (int j = 0; j < 4; ++j) { aq[j] = bq[col]; ak[j] = bk[col]; ac[j] = bc[col]; }

    for (int d = 0; d < DD; ++d) {
        float wq = Wq[d * PP + col];
        float wk = Wk[d * PP + col];
        float wc = Wc[d * PP + col];
#pragma unroll
        for (int j = 0; j < 4; ++j) {
            float a = As[rg * 4 + j][d];
            aq[j] = fmaf(a, wq, aq[j]);
            ak[j] = fmaf(a, wk, ak[j]);
            ac[j] = fmaf(a, wc, ac[j]);
        }
    }
#pragma unroll
    for (int j = 0; j < 4; ++j) {
        long r = row0 + rg * 4 + j;
        Qo[r * PP + col] = aq[j];
        Ko[r * PP + col] = ak[j];
        Ps[rg * 4 + j][col] = ac[j];
    }
    __syncthreads();

    const int w = tid >> 6;
    const int lane = tid & 63;
#pragma unroll
    for (int j = 0; j < 4; ++j) {
        int r = w * 4 + j;
        float v = Ps[r][lane];
        float ss = v * v;
#pragma unroll
        for (int off = 32; off >= 1; off >>= 1) ss += __shfl_xor(ss, off, 64);
        float nrm = fmaxf(sqrtf(ss), 1e-12f);
        PNo[(row0 + r) * PP + lane] = v / nrm;
    }
}

// ---------------------------------------------------------------------------
// K2: scores = Q K^T -> per-row top-8 -> softmax -> incoming gather.
// 16 rows/block (grid = BB*256 = 1024 -> 4 blocks/CU), 36KB LDS.
// ---------------------------------------------------------------------------
__global__ __launch_bounds__(256, 4) void k_topk(
    const float* __restrict__ Q, const float* __restrict__ K,
    const float* __restrict__ states, float* __restrict__ incoming)
{
    __shared__ float Qs[16][PP];       // 4KB
    __shared__ float4 Ks4[128 * 16];   // 32KB, XOR-swizzled float4 slots

    const int tid = threadIdx.x;
    const int b  = blockIdx.x >> 8;          // grid = BB * 256
    const int n0 = (blockIdx.x & 255) << 4;  // 16 rows/block

    {
        const float4* g4 = (const float4*)(Q + ((long)b * NN + n0) * PP);
        ((float4*)(&Qs[0][0]))[tid] = g4[tid];
    }

    const int mg = tid & 31;        // m sub-index (lane within half-wave)
    const int rg = tid >> 5;        // 0..7 -> rows rg+8j, j in {0,1}
    const int m15 = mg & 15;
    float topv[2][TOPK];
    int   topi[2][TOPK];
#pragma unroll
    for (int j = 0; j < 2; ++j)
#pragma unroll
        for (int t = 0; t < TOPK; ++t) { topv[j][t] = -1e30f; topi[j][t] = 0; }

    for (int mt = 0; mt < NN / 128; ++mt) {
        const int m0 = mt << 7;
        __syncthreads();
        {
            const float4* g4 = (const float4*)(K + ((long)b * NN + m0) * PP);
#pragma unroll
            for (int t = 0; t < 8; ++t) {
                int q = tid + t * 256;                 // 0..2047 float4s
                int row = q >> 4, sl = q & 15;
                Ks4[(row << 4) | (sl ^ (row & 15))] = g4[q];
            }
        }
        __syncthreads();

        float s[2][4];
#pragma unroll
        for (int j = 0; j < 2; ++j)
#pragma unroll
            for (int k = 0; k < 4; ++k) s[j][k] = 0.f;

#pragma unroll 4
        for (int sl = 0; sl < 16; ++sl) {              // p = 4*sl
            const int sw = sl ^ m15;
            float4 qv[2], kv[4];
#pragma unroll
            for (int j = 0; j < 2; ++j) qv[j] = *(const float4*)(&Qs[rg + 8 * j][sl << 2]);
#pragma unroll
            for (int k = 0; k < 4; ++k) kv[k] = Ks4[((mg + 32 * k) << 4) + sw];
#pragma unroll
            for (int j = 0; j < 2; ++j)
#pragma unroll
                for (int k = 0; k < 4; ++k) {
                    s[j][k] = fmaf(qv[j].x, kv[k].x, s[j][k]);
                    s[j][k] = fmaf(qv[j].y, kv[k].y, s[j][k]);
                    s[j][k] = fmaf(qv[j].z, kv[k].z, s[j][k]);
                    s[j][k] = fmaf(qv[j].w, kv[k].w, s[j][k]);
                }
        }

        // branchless sorted-desc insert (equal vals keep earlier/lower idx above)
#pragma unroll
        for (int j = 0; j < 2; ++j) {
#pragma unroll
            for (int k = 0; k < 4; ++k) {
                float val = s[j][k];
                int idx = m0 + mg + 32 * k;
                if (val > topv[j][TOPK - 1]) {
                    bool c[TOPK];
#pragma unroll
                    for (int t = 0; t < TOPK; ++t) c[t] = (val > topv[j][t]);
#pragma unroll
                    for (int t = TOPK - 1; t >= 1; --t) {
                        topv[j][t] = c[t - 1] ? topv[j][t - 1] : (c[t] ? val : topv[j][t]);
                        topi[j][t] = c[t - 1] ? topi[j][t - 1] : (c[t] ? idx : topi[j][t]);
                    }
                    topv[j][0] = c[0] ? val : topv[j][0];
                    topi[j][0] = c[0] ? idx : topi[j][0];
                }
            }
        }
    }

    // ---- in-register merge within each half-wave (32 lanes share row rr) ----
#pragma unroll
    for (int j = 0; j < 2; ++j) {
        const int rr = rg + 8 * j;
        float wv[TOPK]; int wi[TOPK];
#pragma unroll
        for (int e = 0; e < TOPK; ++e) {
            float lv = topv[j][0]; int li = topi[j][0];
#pragma unroll
            for (int off = 16; off >= 1; off >>= 1) {
                float ov = __shfl_xor(lv, off, 64);
                int   oi = __shfl_xor(li, off, 64);
                bool tk = (ov > lv) || (ov == lv && oi < li);
                lv = tk ? ov : lv;
                li = tk ? oi : li;
            }
            wv[e] = lv; wi[e] = li;
            bool pop = (topv[j][0] == lv) && (topi[j][0] == li);
#pragma unroll
            for (int t = 0; t < TOPK - 1; ++t) {
                topv[j][t] = pop ? topv[j][t + 1] : topv[j][t];
                topi[j][t] = pop ? topi[j][t + 1] : topi[j][t];
            }
            topv[j][TOPK - 1] = pop ? -1e30f : topv[j][TOPK - 1];
            topi[j][TOPK - 1] = pop ? 0x7FFFFFFF : topi[j][TOPK - 1];
        }

        float mx = wv[0] * 0.125f;
        float ex[TOPK]; float Z = 0.f;
#pragma unroll
        for (int e = 0; e < TOPK; ++e) { ex[e] = expf(wv[e] * 0.125f - mx); Z += ex[e]; }
        float invZ = 1.0f / Z;

        float4 a0 = {0.f, 0.f, 0.f, 0.f}, a1 = {0.f, 0.f, 0.f, 0.f};
#pragma unroll
        for (int e = 0; e < TOPK; ++e) {
            const float4* sp = (const float4*)(states + ((long)b * NN + wi[e]) * DD);
            float4 s0 = sp[mg];
            float4 s1 = sp[mg + 32];
            float we = ex[e] * invZ;
            a0.x = fmaf(we, s0.x, a0.x); a0.y = fmaf(we, s0.y, a0.y);
            a0.z = fmaf(we, s0.z, a0.z); a0.w = fmaf(we, s0.w, a0.w);
            a1.x = fmaf(we, s1.x, a1.x); a1.y = fmaf(we, s1.y, a1.y);
            a1.z = fmaf(we, s1.z, a1.z); a1.w = fmaf(we, s1.w, a1.w);
        }
        float4* op = (float4*)(incoming + ((long)b * NN + n0 + rr) * DD);
        op[mg] = a0;
        op[mg + 32] = a1;
    }
}

// ---------------------------------------------------------------------------
// K3: sim = pn pn^T; cmask = sim>0.7; combined; out = 0.8*inc + 0.2*combined
// ---------------------------------------------------------------------------
#define CAP 64
__global__ __launch_bounds__(256, 4) void k_coal(
    const float* __restrict__ PN, const float* __restrict__ incoming,
    float* __restrict__ outs)
{
    __shared__ float Qs[16][PP];        // 4KB
    __shared__ float4 Ks4[128 * 16];    // 32KB, swizzled
    __shared__ int cnt[16];
    __shared__ unsigned short lst[16][CAP];   // 2KB

    const int tid = threadIdx.x;
    const int b  = blockIdx.x >> 8;
    const int n0 = (blockIdx.x & 255) << 4;

    if (tid < 16) cnt[tid] = 0;
    {
        const float4* g4 = (const float4*)(PN + ((long)b * NN + n0) * PP);
        ((float4*)(&Qs[0][0]))[tid] = g4[tid];
    }

    const int mg = tid & 31;
    const int rg = tid >> 5;
    const int m15 = mg & 15;

    for (int mt = 0; mt < NN / 128; ++mt) {
        const int m0 = mt << 7;
        __syncthreads();
        {
            const float4* g4 = (const float4*)(PN + ((long)b * NN + m0) * PP);
#pragma unroll
            for (int t = 0; t < 8; ++t) {
                int q = tid + t * 256;
                int row = q >> 4, sl = q & 15;
                Ks4[(row << 4) | (sl ^ (row & 15))] = g4[q];
            }
        }
        __syncthreads();

        float s[2][4];
#pragma unroll
        for (int j = 0; j < 2; ++j)
#pragma unroll
            for (int k = 0; k < 4; ++k) s[j][k] = 0.f;

#pragma unroll 4
        for (int sl = 0; sl < 16; ++sl) {
            const int sw = sl ^ m15;
            float4 qv[2], kv[4];
#pragma unroll
            for (int j = 0; j < 2; ++j) qv[j] = *(const float4*)(&Qs[rg + 8 * j][sl << 2]);
#pragma unroll
            for (int k = 0; k < 4; ++k) kv[k] = Ks4[((mg + 32 * k) << 4) + sw];
#pragma unroll
            for (int j = 0; j < 2; ++j)
#pragma unroll
                for (int k = 0; k < 4; ++k) {
                    s[j][k] = fmaf(qv[j].x, kv[k].x, s[j][k]);
                    s[j][k] = fmaf(qv[j].y, kv[k].y, s[j][k]);
                    s[j][k] = fmaf(qv[j].z, kv[k].z, s[j][k]);
                    s[j][k] = fmaf(qv[j].w, kv[k].w, s[j][k]);
                }
        }

#pragma unroll
        for (int j = 0; j < 2; ++j)
#pragma unroll
            for (int k = 0; k < 4; ++k) {
                if (s[j][k] > 0.7f) {
                    int pos = atomicAdd(&cnt[rg + 8 * j], 1);
                    if (pos < CAP) lst[rg + 8 * j][pos] = (unsigned short)(m0 + mg + 32 * k);
                }
            }
    }
    __syncthreads();

    const int w = tid >> 6;
    const int lane = tid & 63;
    for (int rr = w * 4; rr < w * 4 + 4; ++rr) {
        int c = cnt[rr];
        float inv = 1.0f / ((float)c + 1e-8f);
        int cc = (c < CAP) ? c : CAP;
        float ax = 0.f, ay = 0.f, az = 0.f, aw = 0.f;
        for (int i = 0; i < cc; ++i) {
            const float4* ip = (const float4*)(incoming + ((long)b * NN + lst[rr][i]) * DD);
            float4 v = ip[lane];
            ax += v.x; ay += v.y; az += v.z; aw += v.w;
        }
        const float4* self4 = (const float4*)(incoming + ((long)b * NN + n0 + rr) * DD);
        float4 sv = self4[lane];
        float4 o;
        o.x = 0.8f * sv.x + 0.2f * inv * ax;
        o.y = 0.8f * sv.y + 0.2f * inv * ay;
        o.z = 0.8f * sv.z + 0.2f * inv * az;
        o.w = 0.8f * sv.w + 0.2f * inv * aw;
        ((float4*)(outs + ((long)b * NN + n0 + rr) * DD))[lane] = o;
    }
}

// ---------------------------------------------------------------------------
// K4: hdc = tanh(3(out@Wh+bh)); bind; decay-write; cosine read.
// 512 threads, 16 rows/block (grid 1024). Thread owns 8 rows x one float4
// h-quad (h = 4*hq, hq = tid&255) -> acc is float4 acc[8] = 32 VGPR.
// All LDS/global traffic is b128. 48.5KB LDS -> 2 blocks/CU = 4 waves/SIMD.
// ---------------------------------------------------------------------------
__global__ __launch_bounds__(512, 4) void k_mem(
    const float* __restrict__ outs, const float* __restrict__ Wh,
    const float* __restrict__ bh, const float* __restrict__ keys,
    const float* __restrict__ pos_codes, const int* __restrict__ stepp,
    const float* __restrict__ mem,
    float* __restrict__ epi_out, float* __restrict__ sim_out)
{
    __shared__ float Ss[16][DD];    // 16KB
    __shared__ float Wt[8][HH];     // 32KB
    __shared__ float red[8][8][3];

    const int tid = threadIdx.x;
    const long row0 = (long)blockIdx.x * 16;

    {
        const float4* g4 = (const float4*)(outs + row0 * DD);
        float4* s4 = (float4*)(&Ss[0][0]);
        s4[tid] = g4[tid];
        s4[tid + 512] = g4[tid + 512];
    }

    const int hq = tid & 255;       // h-quad: h = 4*hq .. 4*hq+3
    const int rg = tid >> 8;        // rows rg*8+j
    float4 acc[8];
#pragma unroll
    for (int j = 0; j < 8; ++j) { acc[j].x = 0.f; acc[j].y = 0.f; acc[j].z = 0.f; acc[j].w = 0.f; }

    for (int dt = 0; dt < DD / 8; ++dt) {
        __syncthreads();
        {
            const float4* g4 = (const float4*)(Wh + (long)dt * 8 * HH);
            float4* s4 = (float4*)(&Wt[0][0]);
#pragma unroll
            for (int t = 0; t < 4; ++t) s4[tid + t * 512] = g4[tid + t * 512];
        }
        __syncthreads();
#pragma unroll
        for (int dq = 0; dq < 2; ++dq) {
            float sv[8][4];
#pragma unroll
            for (int j = 0; j < 8; ++j) {
                float4 t4 = *(const float4*)(&Ss[rg * 8 + j][dt * 8 + dq * 4]);  // wave-uniform broadcast
                sv[j][0] = t4.x; sv[j][1] = t4.y; sv[j][2] = t4.z; sv[j][3] = t4.w;
            }
#pragma unroll
            for (int d2 = 0; d2 < 4; ++d2) {
                float4 wv = *(const float4*)(&Wt[dq * 4 + d2][hq << 2]);         // b128, contiguous
#pragma unroll
                for (int j = 0; j < 8; ++j) {
                    float a = sv[j][d2];
                    acc[j].x = fmaf(a, wv.x, acc[j].x);
                    acc[j].y = fmaf(a, wv.y, acc[j].y);
                    acc[j].z = fmaf(a, wv.z, acc[j].z);
                    acc[j].w = fmaf(a, wv.w, acc[j].w);
                }
            }
        }
    }

    const int step = stepp[0];
    const int prow = ((step % NCC) + NCC) % NCC;
    const float4 ps = ((const float4*)pos_codes)[prow * (HH / 4) + hq];
    const float4 bb = ((const float4*)bh)[hq];

    float dnp[8], dnn[8], dpp[8];
#pragma unroll
    for (int j = 0; j < 8; ++j) { dnp[j] = 0.f; dnn[j] = 0.f; dpp[j] = 0.f; }

#pragma unroll
    for (int j = 0; j < 8; ++j) {
        long row = row0 + rg * 8 + j;
        int n = (int)(row & (NN - 1));
        float4 kv = ((const float4*)keys)[n * (HH / 4) + hq];
        float4 mv = ((const float4*)mem)[row * (HH / 4) + hq];
        float4 o, pe;
        // tanh(3y) = 1 - 2/(exp(6y)+1); saturates correctly at +/-inf
        {
            float e0 = __expf(6.0f * (acc[j].x + bb.x));
            float e1 = __expf(6.0f * (acc[j].y + bb.y));
            float e2 = __expf(6.0f * (acc[j].z + bb.z));
            float e3 = __expf(6.0f * (acc[j].w + bb.w));
            float h0 = 1.0f - __fdividef(2.0f, e0 + 1.0f);
            float h1 = 1.0f - __fdividef(2.0f, e1 + 1.0f);
            float h2 = 1.0f - __fdividef(2.0f, e2 + 1.0f);
            float h3 = 1.0f - __fdividef(2.0f, e3 + 1.0f);
            pe.x = h0 * kv.x; pe.y = h1 * kv.y; pe.z = h2 * kv.z; pe.w = h3 * kv.w;
        }
        o.x = 0.95f * mv.x + 0.05f * (pe.x * ps.x);
        o.y = 0.95f * mv.y + 0.05f * (pe.y * ps.y);
        o.z = 0.95f * mv.z + 0.05f * (pe.z * ps.z);
        o.w = 0.95f * mv.w + 0.05f * (pe.w * ps.w);
        ((float4*)epi_out)[row * (HH / 4) + hq] = o;
        dnp[j] += o.x * pe.x + o.y * pe.y + o.z * pe.z + o.w * pe.w;
        dnn[j] += o.x * o.x + o.y * o.y + o.z * o.z + o.w * o.w;
        dpp[j] += pe.x * pe.x + pe.y * pe.y + pe.z * pe.z + pe.w * pe.w;
    }

#pragma unroll
    for (int j = 0; j < 8; ++j) {
#pragma unroll
        for (int off = 32; off >= 1; off >>= 1) {
            dnp[j] += __shfl_xor(dnp[j], off, 64);
            dnn[j] += __shfl_xor(dnn[j], off, 64);
            dpp[j] += __shfl_xor(dpp[j], off, 64);
        }
    }
    const int w = tid >> 6;         // 0..7; waves 0-3 -> rg 0, waves 4-7 -> rg 1
    const int lane = tid & 63;
    if (lane == 0) {
#pragma unroll
        for (int j = 0; j < 8; ++j) {
            red[w][j][0] = dnp[j]; red[w][j][1] = dnn[j]; red[w][j][2] = dpp[j];
        }
    }
    __syncthreads();
    if (tid < 16) {
        int rgp = tid >> 3, j = tid & 7;
        float dot = 0.f, nn = 0.f, pp = 0.f;
#pragma unroll
        for (int ww = 0; ww < 4; ++ww) {
            dot += red[rgp * 4 + ww][j][0];
            nn  += red[rgp * 4 + ww][j][1];
            pp  += red[rgp * 4 + ww][j][2];
        }
        float na = fmaxf(sqrtf(nn), 1e-8f);
        float nb = fmaxf(sqrtf(pp), 1e-8f);
        sim_out[row0 + rgp * 8 + j] = dot / (na * nb);
    }
}

// ---------------------------------------------------------------------------
extern "C" void kernel_launch(void* const* d_in, const int* in_sizes, int n_in,
                              void* d_out, int out_size, void* d_ws, size_t ws_size,
                              hipStream_t stream)
{
    const float* states  = (const float*)d_in[0];
    const float* actions = (const float*)d_in[1];
    const float* mem     = (const float*)d_in[2];
    const float* Wq = (const float*)d_in[3];
    const float* bq = (const float*)d_in[4];
    const float* Wk = (const float*)d_in[5];
    const float* bk = (const float*)d_in[6];
    const float* Wc = (const float*)d_in[7];
    const float* bc = (const float*)d_in[8];
    const float* Wh = (const float*)d_in[9];
    const float* bh = (const float*)d_in[10];
    const float* keys = (const float*)d_in[11];
    const float* pos  = (const float*)d_in[12];
    const int*   step = (const int*)d_in[13];

    float* ws = (float*)d_ws;
    float* Q        = ws;                    // 1,048,576 floats
    float* K        = ws + 1048576;          // 1,048,576
    float* PN       = ws + 2097152;          // 1,048,576
    float* incoming = ws + 3145728;          // 4,194,304

    float* outs = (float*)d_out;                       // B*N*D
    float* epi  = outs + (long)BB * NN * DD;           // B*N*H
    float* simo = epi + (long)BB * NN * HH;            // B*N

    hipLaunchKernelGGL(k_proj, dim3(BB * NN / 16), dim3(256), 0, stream,
                       actions, Wq, bq, Wk, bk, Wc, bc, Q, K, PN);
    hipLaunchKernelGGL(k_topk, dim3(BB * (NN / 16)), dim3(256), 0, stream,
                       Q, K, states, incoming);
    hipLaunchKernelGGL(k_coal, dim3(BB * (NN / 16)), dim3(256), 0, stream,
                       PN, incoming, outs);
    hipLaunchKernelGGL(k_mem, dim3(BB * NN / 16), dim3(512), 0, stream,
                       outs, Wh, bh, keys, pos, step, mem, epi, simo);
}

// Round 8
// 572.014 us; speedup vs baseline: 1.1708x; 1.0215x over previous
//
#include <hip/hip_runtime.h>

#define BB 4
#define NN 4096
#define DD 256
#define PP 64
#define HH 1024
#define NCC 256
#define TOPK 8

// global -> LDS direct (16B/lane), no VGPR round trip.
__device__ __forceinline__ void gload_lds16(const float* g, float* l) {
    __builtin_amdgcn_global_load_lds(
        (const __attribute__((address_space(1))) void*)g,
        (__attribute__((address_space(3))) void*)l, 16, 0, 0);
}

// ---------------------------------------------------------------------------
// K1: Q = A@Wq+bq, K = A@Wk+bk, proj = A@Wc+bc, pn = proj/max(||proj||,1e-12)
// ---------------------------------------------------------------------------
__global__ __launch_bounds__(256) void k_proj(
    const float* __restrict__ act,
    const float* __restrict__ Wq, const float* __restrict__ bq,
    const float* __restrict__ Wk, const float* __restrict__ bk,
    const float* __restrict__ Wc, const float* __restrict__ bc,
    float* __restrict__ Qo, float* __restrict__ Ko, float* __restrict__ PNo)
{
    __shared__ float As[16][DD];   // 16KB
    __shared__ float Ps[16][PP];   // 4KB
    const int tid = threadIdx.x;
    const long row0 = (long)blockIdx.x * 16;

    {
        const float4* g4 = (const float4*)(act + row0 * DD);
        float4* s4 = (float4*)(&As[0][0]);
#pragma unroll
        for (int i = 0; i < 4; ++i) s4[tid + i * 256] = g4[tid + i * 256];
    }
    __syncthreads();

    const int col = tid & 63;
    const int rg  = tid >> 6;   // 0..3 -> rows rg*4+j
    float aq[4], ak[4], ac[4];
#pragma unroll
    for (int j = 0; j < 4; ++j) { aq[j] = bq[col]; ak[j] = bk[col]; ac[j] = bc[col]; }

    for (int d = 0; d < DD; ++d) {
        float wq = Wq[d * PP + col];
        float wk = Wk[d * PP + col];
        float wc = Wc[d * PP + col];
#pragma unroll
        for (int j = 0; j < 4; ++j) {
            float a = As[rg * 4 + j][d];
            aq[j] = fmaf(a, wq, aq[j]);
            ak[j] = fmaf(a, wk, ak[j]);
            ac[j] = fmaf(a, wc, ac[j]);
        }
    }
#pragma unroll
    for (int j = 0; j < 4; ++j) {
        long r = row0 + rg * 4 + j;
        Qo[r * PP + col] = aq[j];
        Ko[r * PP + col] = ak[j];
        Ps[rg * 4 + j][col] = ac[j];
    }
    __syncthreads();

    const int w = tid >> 6;
    const int lane = tid & 63;
#pragma unroll
    for (int j = 0; j < 4; ++j) {
        int r = w * 4 + j;
        float v = Ps[r][lane];
        float ss = v * v;
#pragma unroll
        for (int off = 32; off >= 1; off >>= 1) ss += __shfl_xor(ss, off, 64);
        float nrm = fmaxf(sqrtf(ss), 1e-12f);
        PNo[(row0 + r) * PP + lane] = v / nrm;
    }
}

// ---------------------------------------------------------------------------
// K2: scores = Q K^T -> per-row top-8 -> softmax -> incoming gather.
// Staging via global_load_lds with pre-swizzled SOURCE (linear LDS dest);
// read side applies the same XOR (involution). 36KB LDS -> 4 blocks/CU.
// ---------------------------------------------------------------------------
__global__ __launch_bounds__(256, 4) void k_topk(
    const float* __restrict__ Q, const float* __restrict__ K,
    const float* __restrict__ states, float* __restrict__ incoming)
{
    __shared__ float Qs[16][PP];       // 4KB
    __shared__ float Ks[128 * 16 * 4]; // 32KB; slot q holds K[row][4*((q&15)^(row&15))..]

    const int tid = threadIdx.x;
    const int b  = blockIdx.x >> 8;          // grid = BB * 256
    const int n0 = (blockIdx.x & 255) << 4;  // 16 rows/block
    const int wid = tid >> 6;

    {
        const float4* g4 = (const float4*)(Q + ((long)b * NN + n0) * PP);
        ((float4*)(&Qs[0][0]))[tid] = g4[tid];
    }

    const int mg = tid & 31;        // m sub-index (lane within half-wave)
    const int rg = tid >> 5;        // 0..7 -> rows rg+8j, j in {0,1}
    const int m15 = mg & 15;
    float topv[2][TOPK];
    int   topi[2][TOPK];
#pragma unroll
    for (int j = 0; j < 2; ++j)
#pragma unroll
        for (int t = 0; t < TOPK; ++t) { topv[j][t] = -1e30f; topi[j][t] = 0; }

    for (int mt = 0; mt < NN / 128; ++mt) {
        const int m0 = mt << 7;
        __syncthreads();
        {
            const float* kb = K + ((long)b * NN + m0) * PP;
#pragma unroll
            for (int t = 0; t < 8; ++t) {
                int q = t * 256 + tid;                // dest float4-slot
                int row = q >> 4, psl = q & 15;
                int ss = psl ^ (row & 15);            // inverse-swizzled source
                gload_lds16(kb + row * PP + ss * 4,
                            Ks + (((t * 256 + (wid << 6)) << 2)));
            }
        }
        __syncthreads();   // compiler drains vmcnt(0) before s_barrier

        float s[2][4];
#pragma unroll
        for (int j = 0; j < 2; ++j)
#pragma unroll
            for (int k = 0; k < 4; ++k) s[j][k] = 0.f;

#pragma unroll 4
        for (int sl = 0; sl < 16; ++sl) {              // p = 4*sl
            const int sw = sl ^ m15;
            float4 qv[2], kv[4];
#pragma unroll
            for (int j = 0; j < 2; ++j) qv[j] = *(const float4*)(&Qs[rg + 8 * j][sl << 2]);
#pragma unroll
            for (int k = 0; k < 4; ++k)
                kv[k] = *(const float4*)(&Ks[((((mg + 32 * k) << 4) + sw) << 2)]);
#pragma unroll
            for (int j = 0; j < 2; ++j)
#pragma unroll
                for (int k = 0; k < 4; ++k) {
                    s[j][k] = fmaf(qv[j].x, kv[k].x, s[j][k]);
                    s[j][k] = fmaf(qv[j].y, kv[k].y, s[j][k]);
                    s[j][k] = fmaf(qv[j].z, kv[k].z, s[j][k]);
                    s[j][k] = fmaf(qv[j].w, kv[k].w, s[j][k]);
                }
        }

        // branchless sorted-desc insert (equal vals keep earlier/lower idx above)
#pragma unroll
        for (int j = 0; j < 2; ++j) {
#pragma unroll
            for (int k = 0; k < 4; ++k) {
                float val = s[j][k];
                int idx = m0 + mg + 32 * k;
                if (val > topv[j][TOPK - 1]) {
                    bool c[TOPK];
#pragma unroll
                    for (int t = 0; t < TOPK; ++t) c[t] = (val > topv[j][t]);
#pragma unroll
                    for (int t = TOPK - 1; t >= 1; --t) {
                        topv[j][t] = c[t - 1] ? topv[j][t - 1] : (c[t] ? val : topv[j][t]);
                        topi[j][t] = c[t - 1] ? topi[j][t - 1] : (c[t] ? idx : topi[j][t]);
                    }
                    topv[j][0] = c[0] ? val : topv[j][0];
                    topi[j][0] = c[0] ? idx : topi[j][0];
                }
            }
        }
    }

    // ---- in-register merge within each half-wave (32 lanes share row rr) ----
#pragma unroll
    for (int j = 0; j < 2; ++j) {
        const int rr = rg + 8 * j;
        float wv[TOPK]; int wi[TOPK];
#pragma unroll
        for (int e = 0; e < TOPK; ++e) {
            float lv = topv[j][0]; int li = topi[j][0];
#pragma unroll
            for (int off = 16; off >= 1; off >>= 1) {
                float ov = __shfl_xor(lv, off, 64);
                int   oi = __shfl_xor(li, off, 64);
                bool tk = (ov > lv) || (ov == lv && oi < li);
                lv = tk ? ov : lv;
                li = tk ? oi : li;
            }
            wv[e] = lv; wi[e] = li;
            bool pop = (topv[j][0] == lv) && (topi[j][0] == li);
#pragma unroll
            for (int t = 0; t < TOPK - 1; ++t) {
                topv[j][t] = pop ? topv[j][t + 1] : topv[j][t];
                topi[j][t] = pop ? topi[j][t + 1] : topi[j][t];
            }
            topv[j][TOPK - 1] = pop ? -1e30f : topv[j][TOPK - 1];
            topi[j][TOPK - 1] = pop ? 0x7FFFFFFF : topi[j][TOPK - 1];
        }

        float mx = wv[0] * 0.125f;
        float ex[TOPK]; float Z = 0.f;
#pragma unroll
        for (int e = 0; e < TOPK; ++e) { ex[e] = expf(wv[e] * 0.125f - mx); Z += ex[e]; }
        float invZ = 1.0f / Z;

        float4 a0 = {0.f, 0.f, 0.f, 0.f}, a1 = {0.f, 0.f, 0.f, 0.f};
#pragma unroll
        for (int e = 0; e < TOPK; ++e) {
            const float4* sp = (const float4*)(states + ((long)b * NN + wi[e]) * DD);
            float4 s0 = sp[mg];
            float4 s1 = sp[mg + 32];
            float we = ex[e] * invZ;
            a0.x = fmaf(we, s0.x, a0.x); a0.y = fmaf(we, s0.y, a0.y);
            a0.z = fmaf(we, s0.z, a0.z); a0.w = fmaf(we, s0.w, a0.w);
            a1.x = fmaf(we, s1.x, a1.x); a1.y = fmaf(we, s1.y, a1.y);
            a1.z = fmaf(we, s1.z, a1.z); a1.w = fmaf(we, s1.w, a1.w);
        }
        float4* op = (float4*)(incoming + ((long)b * NN + n0 + rr) * DD);
        op[mg] = a0;
        op[mg + 32] = a1;
    }
}

// ---------------------------------------------------------------------------
// K3: sim = pn pn^T; cmask = sim>0.7; combined; out = 0.8*inc + 0.2*combined
// Same global_load_lds staging with pre-swizzled source.
// ---------------------------------------------------------------------------
#define CAP 64
__global__ __launch_bounds__(256, 4) void k_coal(
    const float* __restrict__ PN, const float* __restrict__ incoming,
    float* __restrict__ outs)
{
    __shared__ float Qs[16][PP];        // 4KB
    __shared__ float Ks[128 * 16 * 4];  // 32KB
    __shared__ int cnt[16];
    __shared__ unsigned short lst[16][CAP];   // 2KB

    const int tid = threadIdx.x;
    const int b  = blockIdx.x >> 8;
    const int n0 = (blockIdx.x & 255) << 4;
    const int wid = tid >> 6;

    if (tid < 16) cnt[tid] = 0;
    {
        const float4* g4 = (const float4*)(PN + ((long)b * NN + n0) * PP);
        ((float4*)(&Qs[0][0]))[tid] = g4[tid];
    }

    const int mg = tid & 31;
    const int rg = tid >> 5;
    const int m15 = mg & 15;

    for (int mt = 0; mt < NN / 128; ++mt) {
        const int m0 = mt << 7;
        __syncthreads();
        {
            const float* kb = PN + ((long)b * NN + m0) * PP;
#pragma unroll
            for (int t = 0; t < 8; ++t) {
                int q = t * 256 + tid;
                int row = q >> 4, psl = q & 15;
                int ss = psl ^ (row & 15);
                gload_lds16(kb + row * PP + ss * 4,
                            Ks + (((t * 256 + (wid << 6)) << 2)));
            }
        }
        __syncthreads();

        float s[2][4];
#pragma unroll
        for (int j = 0; j < 2; ++j)
#pragma unroll
            for (int k = 0; k < 4; ++k) s[j][k] = 0.f;

#pragma unroll 4
        for (int sl = 0; sl < 16; ++sl) {
            const int sw = sl ^ m15;
            float4 qv[2], kv[4];
#pragma unroll
            for (int j = 0; j < 2; ++j) qv[j] = *(const float4*)(&Qs[rg + 8 * j][sl << 2]);
#pragma unroll
            for (int k = 0; k < 4; ++k)
                kv[k] = *(const float4*)(&Ks[((((mg + 32 * k) << 4) + sw) << 2)]);
#pragma unroll
            for (int j = 0; j < 2; ++j)
#pragma unroll
                for (int k = 0; k < 4; ++k) {
                    s[j][k] = fmaf(qv[j].x, kv[k].x, s[j][k]);
                    s[j][k] = fmaf(qv[j].y, kv[k].y, s[j][k]);
                    s[j][k] = fmaf(qv[j].z, kv[k].z, s[j][k]);
                    s[j][k] = fmaf(qv[j].w, kv[k].w, s[j][k]);
                }
        }

#pragma unroll
        for (int j = 0; j < 2; ++j)
#pragma unroll
            for (int k = 0; k < 4; ++k) {
                if (s[j][k] > 0.7f) {
                    int pos = atomicAdd(&cnt[rg + 8 * j], 1);
                    if (pos < CAP) lst[rg + 8 * j][pos] = (unsigned short)(m0 + mg + 32 * k);
                }
            }
    }
    __syncthreads();

    const int w = tid >> 6;
    const int lane = tid & 63;
    for (int rr = w * 4; rr < w * 4 + 4; ++rr) {
        int c = cnt[rr];
        float inv = 1.0f / ((float)c + 1e-8f);
        int cc = (c < CAP) ? c : CAP;
        float ax = 0.f, ay = 0.f, az = 0.f, aw = 0.f;
        for (int i = 0; i < cc; ++i) {
            const float4* ip = (const float4*)(incoming + ((long)b * NN + lst[rr][i]) * DD);
            float4 v = ip[lane];
            ax += v.x; ay += v.y; az += v.z; aw += v.w;
        }
        const float4* self4 = (const float4*)(incoming + ((long)b * NN + n0 + rr) * DD);
        float4 sv = self4[lane];
        float4 o;
        o.x = 0.8f * sv.x + 0.2f * inv * ax;
        o.y = 0.8f * sv.y + 0.2f * inv * ay;
        o.z = 0.8f * sv.z + 0.2f * inv * az;
        o.w = 0.8f * sv.w + 0.2f * inv * aw;
        ((float4*)(outs + ((long)b * NN + n0 + rr) * DD))[lane] = o;
    }
}

// ---------------------------------------------------------------------------
// K4: hdc = tanh(3(out@Wh+bh)); bind; decay-write; cosine read.
// 512 threads, 16 rows/block; thread owns 8 rows x one float4 h-quad.
// ---------------------------------------------------------------------------
__global__ __launch_bounds__(512, 4) void k_mem(
    const float* __restrict__ outs, const float* __restrict__ Wh,
    const float* __restrict__ bh, const float* __restrict__ keys,
    const float* __restrict__ pos_codes, const int* __restrict__ stepp,
    const float* __restrict__ mem,
    float* __restrict__ epi_out, float* __restrict__ sim_out)
{
    __shared__ float Ss[16][DD];    // 16KB
    __shared__ float Wt[8][HH];     // 32KB
    __shared__ float red[8][8][3];

    const int tid = threadIdx.x;
    const long row0 = (long)blockIdx.x * 16;

    {
        const float4* g4 = (const float4*)(outs + row0 * DD);
        float4* s4 = (float4*)(&Ss[0][0]);
        s4[tid] = g4[tid];
        s4[tid + 512] = g4[tid + 512];
    }

    const int hq = tid & 255;       // h-quad: h = 4*hq .. 4*hq+3
    const int rg = tid >> 8;        // rows rg*8+j
    float4 acc[8];
#pragma unroll
    for (int j = 0; j < 8; ++j) { acc[j].x = 0.f; acc[j].y = 0.f; acc[j].z = 0.f; acc[j].w = 0.f; }

    for (int dt = 0; dt < DD / 8; ++dt) {
        __syncthreads();
        {
            const float4* g4 = (const float4*)(Wh + (long)dt * 8 * HH);
            float4* s4 = (float4*)(&Wt[0][0]);
#pragma unroll
            for (int t = 0; t < 4; ++t) s4[tid + t * 512] = g4[tid + t * 512];
        }
        __syncthreads();
#pragma unroll
        for (int dq = 0; dq < 2; ++dq) {
            float sv[8][4];
#pragma unroll
            for (int j = 0; j < 8; ++j) {
                float4 t4 = *(const float4*)(&Ss[rg * 8 + j][dt * 8 + dq * 4]);  // wave-uniform broadcast
                sv[j][0] = t4.x; sv[j][1] = t4.y; sv[j][2] = t4.z; sv[j][3] = t4.w;
            }
#pragma unroll
            for (int d2 = 0; d2 < 4; ++d2) {
                float4 wv = *(const float4*)(&Wt[dq * 4 + d2][hq << 2]);         // b128, contiguous
#pragma unroll
                for (int j = 0; j < 8; ++j) {
                    float a = sv[j][d2];
                    acc[j].x = fmaf(a, wv.x, acc[j].x);
                    acc[j].y = fmaf(a, wv.y, acc[j].y);
                    acc[j].z = fmaf(a, wv.z, acc[j].z);
                    acc[j].w = fmaf(a, wv.w, acc[j].w);
                }
            }
        }
    }

    const int step = stepp[0];
    const int prow = ((step % NCC) + NCC) % NCC;
    const float4 ps = ((const float4*)pos_codes)[prow * (HH / 4) + hq];
    const float4 bb = ((const float4*)bh)[hq];

    float dnp[8], dnn[8], dpp[8];
#pragma unroll
    for (int j = 0; j < 8; ++j) { dnp[j] = 0.f; dnn[j] = 0.f; dpp[j] = 0.f; }

#pragma unroll
    for (int j = 0; j < 8; ++j) {
        long row = row0 + rg * 8 + j;
        int n = (int)(row & (NN - 1));
        float4 kv = ((const float4*)keys)[n * (HH / 4) + hq];
        float4 mv = ((const float4*)mem)[row * (HH / 4) + hq];
        float4 o, pe;
        // tanh(3y) = 1 - 2/(exp(6y)+1); saturates correctly at +/-inf
        {
            float e0 = __expf(6.0f * (acc[j].x + bb.x));
            float e1 = __expf(6.0f * (acc[j].y + bb.y));
            float e2 = __expf(6.0f * (acc[j].z + bb.z));
            float e3 = __expf(6.0f * (acc[j].w + bb.w));
            float h0 = 1.0f - __fdividef(2.0f, e0 + 1.0f);
            float h1 = 1.0f - __fdividef(2.0f, e1 + 1.0f);
            float h2 = 1.0f - __fdividef(2.0f, e2 + 1.0f);
            float h3 = 1.0f - __fdividef(2.0f, e3 + 1.0f);
            pe.x = h0 * kv.x; pe.y = h1 * kv.y; pe.z = h2 * kv.z; pe.w = h3 * kv.w;
        }
        o.x = 0.95f * mv.x + 0.05f * (pe.x * ps.x);
        o.y = 0.95f * mv.y + 0.05f * (pe.y * ps.y);
        o.z = 0.95f * mv.z + 0.05f * (pe.z * ps.z);
        o.w = 0.95f * mv.w + 0.05f * (pe.w * ps.w);
        ((float4*)epi_out)[row * (HH / 4) + hq] = o;
        dnp[j] += o.x * pe.x + o.y * pe.y + o.z * pe.z + o.w * pe.w;
        dnn[j] += o.x * o.x + o.y * o.y + o.z * o.z + o.w * o.w;
        dpp[j] += pe.x * pe.x + pe.y * pe.y + pe.z * pe.z + pe.w * pe.w;
    }

#pragma unroll
    for (int j = 0; j < 8; ++j) {
#pragma unroll
        for (int off = 32; off >= 1; off >>= 1) {
            dnp[j] += __shfl_xor(dnp[j], off, 64);
            dnn[j] += __shfl_xor(dnn[j], off, 64);
            dpp[j] += __shfl_xor(dpp[j], off, 64);
        }
    }
    const int w = tid >> 6;
    const int lane = tid & 63;
    if (lane == 0) {
#pragma unroll
        for (int j = 0; j < 8; ++j) {
            red[w][j][0] = dnp[j]; red[w][j][1] = dnn[j]; red[w][j][2] = dpp[j];
        }
    }
    __syncthreads();
    if (tid < 16) {
        int rgp = tid >> 3, j = tid & 7;
        float dot = 0.f, nn = 0.f, pp = 0.f;
#pragma unroll
        for (int ww = 0; ww < 4; ++ww) {
            dot += red[rgp * 4 + ww][j][0];
            nn  += red[rgp * 4 + ww][j][1];
            pp  += red[rgp * 4 + ww][j][2];
        }
        float na = fmaxf(sqrtf(nn), 1e-8f);
        float nb = fmaxf(sqrtf(pp), 1e-8f);
        sim_out[row0 + rgp * 8 + j] = dot / (na * nb);
    }
}

// ---------------------------------------------------------------------------
extern "C" void kernel_launch(void* const* d_in, const int* in_sizes, int n_in,
                              void* d_out, int out_size, void* d_ws, size_t ws_size,
                              hipStream_t stream)
{
    const float* states  = (const float*)d_in[0];
    const float* actions = (const float*)d_in[1];
    const float* mem     = (const float*)d_in[2];
    const float* Wq = (const float*)d_in[3];
    const float* bq = (const float*)d_in[4];
    const float* Wk = (const float*)d_in[5];
    const float* bk = (const float*)d_in[6];
    const float* Wc = (const float*)d_in[7];
    const float* bc = (const float*)d_in[8];
    const float* Wh = (const float*)d_in[9];
    const float* bh = (const float*)d_in[10];
    const float* keys = (const float*)d_in[11];
    const float* pos  = (const float*)d_in[12];
    const int*   step = (const int*)d_in[13];

    float* ws = (float*)d_ws;
    float* Q        = ws;                    // 1,048,576 floats
    float* K        = ws + 1048576;          // 1,048,576
    float* PN       = ws + 2097152;          // 1,048,576
    float* incoming = ws + 3145728;          // 4,194,304

    float* outs = (float*)d_out;                       // B*N*D
    float* epi  = outs + (long)BB * NN * DD;           // B*N*H
    float* simo = epi + (long)BB * NN * HH;            // B*N

    hipLaunchKernelGGL(k_proj, dim3(BB * NN / 16), dim3(256), 0, stream,
                       actions, Wq, bq, Wk, bk, Wc, bc, Q, K, PN);
    hipLaunchKernelGGL(k_topk, dim3(BB * (NN / 16)), dim3(256), 0, stream,
                       Q, K, states, incoming);
    hipLaunchKernelGGL(k_coal, dim3(BB * (NN / 16)), dim3(256), 0, stream,
                       PN, incoming, outs);
    hipLaunchKernelGGL(k_mem, dim3(BB * NN / 16), dim3(512), 0, stream,
                       outs, Wh, bh, keys, pos, step, mem, epi, simo);
}

// Round 9
// 350.701 us; speedup vs baseline: 1.9097x; 1.6311x over previous
//
#include <hip/hip_runtime.h>

#define BB 4
#define NN 4096
#define DD 256
#define PP 64
#define HH 1024
#define NCC 256
#define TOPK 8

typedef __attribute__((ext_vector_type(8))) short s8v;   // 8 bf16
typedef __attribute__((ext_vector_type(4))) float f4v;   // 4 f32

__device__ __forceinline__ void gload_lds16(const float* g, float* l) {
    __builtin_amdgcn_global_load_lds(
        (const __attribute__((address_space(1))) void*)g,
        (__attribute__((address_space(3))) void*)l, 16, 0, 0);
}
__device__ __forceinline__ void gload_lds16b(const unsigned short* g, unsigned short* l) {
    __builtin_amdgcn_global_load_lds(
        (const __attribute__((address_space(1))) void*)g,
        (__attribute__((address_space(3))) void*)l, 16, 0, 0);
}
__device__ __forceinline__ unsigned short f2b(float f) {   // RNE f32->bf16
    unsigned int u = __float_as_uint(f);
    unsigned int r = (u + 0x7FFFu + ((u >> 16) & 1u)) >> 16;
    return (unsigned short)r;
}

// ---------------------------------------------------------------------------
// K1: Q,K projections (fp32) + pn (bf16) + Whb_t transpose-convert (bf16).
// grid = 1024 blocks; block bid also converts Wh column h=bid.
// ---------------------------------------------------------------------------
__global__ __launch_bounds__(256) void k_proj(
    const float* __restrict__ act,
    const float* __restrict__ Wq, const float* __restrict__ bq,
    const float* __restrict__ Wk, const float* __restrict__ bk,
    const float* __restrict__ Wc, const float* __restrict__ bc,
    const float* __restrict__ Wh,
    float* __restrict__ Qo, float* __restrict__ Ko,
    unsigned short* __restrict__ PNb, unsigned short* __restrict__ Whb)
{
    __shared__ float As[16][DD];   // 16KB
    __shared__ float Ps[16][PP];   // 4KB
    const int tid = threadIdx.x;
    const long row0 = (long)blockIdx.x * 16;

    {
        const float4* g4 = (const float4*)(act + row0 * DD);
        float4* s4 = (float4*)(&As[0][0]);
#pragma unroll
        for (int i = 0; i < 4; ++i) s4[tid + i * 256] = g4[tid + i * 256];
    }
    // Wh transpose-convert: Whb[h][d] = bf16(Wh[d][h]), h = blockIdx.x
    {
        int h = blockIdx.x;                      // grid == HH
        Whb[(long)h * DD + tid] = f2b(Wh[(long)tid * HH + h]);
    }
    __syncthreads();

    const int col = tid & 63;
    const int rg  = tid >> 6;   // 0..3 -> rows rg*4+j
    float aq[4], ak[4], ac[4];
#pragma unroll
    for (int j = 0; j < 4; ++j) { aq[j] = bq[col]; ak[j] = bk[col]; ac[j] = bc[col]; }

    for (int d = 0; d < DD; ++d) {
        float wq = Wq[d * PP + col];
        float wk = Wk[d * PP + col];
        float wc = Wc[d * PP + col];
#pragma unroll
        for (int j = 0; j < 4; ++j) {
            float a = As[rg * 4 + j][d];
            aq[j] = fmaf(a, wq, aq[j]);
            ak[j] = fmaf(a, wk, ak[j]);
            ac[j] = fmaf(a, wc, ac[j]);
        }
    }
#pragma unroll
    for (int j = 0; j < 4; ++j) {
        long r = row0 + rg * 4 + j;
        Qo[r * PP + col] = aq[j];
        Ko[r * PP + col] = ak[j];
        Ps[rg * 4 + j][col] = ac[j];
    }
    __syncthreads();

    const int w = tid >> 6;
    const int lane = tid & 63;
#pragma unroll
    for (int j = 0; j < 4; ++j) {
        int r = w * 4 + j;
        float v = Ps[r][lane];
        float ss = v * v;
#pragma unroll
        for (int off = 32; off >= 1; off >>= 1) ss += __shfl_xor(ss, off, 64);
        float nrm = fmaxf(sqrtf(ss), 1e-12f);
        PNb[(row0 + r) * PP + lane] = f2b(v / nrm);
    }
}

// ---------------------------------------------------------------------------
// K2: scores = Q K^T (fp32) -> per-row top-8 -> softmax -> gather. UNCHANGED.
// ---------------------------------------------------------------------------
__global__ __launch_bounds__(256, 4) void k_topk(
    const float* __restrict__ Q, const float* __restrict__ K,
    const float* __restrict__ states, float* __restrict__ incoming)
{
    __shared__ float Qs[16][PP];       // 4KB
    __shared__ float Ks[128 * 16 * 4]; // 32KB; slot q holds K[row][4*((q&15)^(row&15))..]

    const int tid = threadIdx.x;
    const int b  = blockIdx.x >> 8;          // grid = BB * 256
    const int n0 = (blockIdx.x & 255) << 4;  // 16 rows/block
    const int wid = tid >> 6;

    {
        const float4* g4 = (const float4*)(Q + ((long)b * NN + n0) * PP);
        ((float4*)(&Qs[0][0]))[tid] = g4[tid];
    }

    const int mg = tid & 31;
    const int rg = tid >> 5;
    const int m15 = mg & 15;
    float topv[2][TOPK];
    int   topi[2][TOPK];
#pragma unroll
    for (int j = 0; j < 2; ++j)
#pragma unroll
        for (int t = 0; t < TOPK; ++t) { topv[j][t] = -1e30f; topi[j][t] = 0; }

    for (int mt = 0; mt < NN / 128; ++mt) {
        const int m0 = mt << 7;
        __syncthreads();
        {
            const float* kb = K + ((long)b * NN + m0) * PP;
#pragma unroll
            for (int t = 0; t < 8; ++t) {
                int q = t * 256 + tid;
                int row = q >> 4, psl = q & 15;
                int ss = psl ^ (row & 15);
                gload_lds16(kb + row * PP + ss * 4,
                            Ks + (((t * 256 + (wid << 6)) << 2)));
            }
        }
        __syncthreads();

        float s[2][4];
#pragma unroll
        for (int j = 0; j < 2; ++j)
#pragma unroll
            for (int k = 0; k < 4; ++k) s[j][k] = 0.f;

#pragma unroll 4
        for (int sl = 0; sl < 16; ++sl) {
            const int sw = sl ^ m15;
            float4 qv[2], kv[4];
#pragma unroll
            for (int j = 0; j < 2; ++j) qv[j] = *(const float4*)(&Qs[rg + 8 * j][sl << 2]);
#pragma unroll
            for (int k = 0; k < 4; ++k)
                kv[k] = *(const float4*)(&Ks[((((mg + 32 * k) << 4) + sw) << 2)]);
#pragma unroll
            for (int j = 0; j < 2; ++j)
#pragma unroll
                for (int k = 0; k < 4; ++k) {
                    s[j][k] = fmaf(qv[j].x, kv[k].x, s[j][k]);
                    s[j][k] = fmaf(qv[j].y, kv[k].y, s[j][k]);
                    s[j][k] = fmaf(qv[j].z, kv[k].z, s[j][k]);
                    s[j][k] = fmaf(qv[j].w, kv[k].w, s[j][k]);
                }
        }

#pragma unroll
        for (int j = 0; j < 2; ++j) {
#pragma unroll
            for (int k = 0; k < 4; ++k) {
                float val = s[j][k];
                int idx = m0 + mg + 32 * k;
                if (val > topv[j][TOPK - 1]) {
                    bool c[TOPK];
#pragma unroll
                    for (int t = 0; t < TOPK; ++t) c[t] = (val > topv[j][t]);
#pragma unroll
                    for (int t = TOPK - 1; t >= 1; --t) {
                        topv[j][t] = c[t - 1] ? topv[j][t - 1] : (c[t] ? val : topv[j][t]);
                        topi[j][t] = c[t - 1] ? topi[j][t - 1] : (c[t] ? idx : topi[j][t]);
                    }
                    topv[j][0] = c[0] ? val : topv[j][0];
                    topi[j][0] = c[0] ? idx : topi[j][0];
                }
            }
        }
    }

#pragma unroll
    for (int j = 0; j < 2; ++j) {
        const int rr = rg + 8 * j;
        float wv[TOPK]; int wi[TOPK];
#pragma unroll
        for (int e = 0; e < TOPK; ++e) {
            float lv = topv[j][0]; int li = topi[j][0];
#pragma unroll
            for (int off = 16; off >= 1; off >>= 1) {
                float ov = __shfl_xor(lv, off, 64);
                int   oi = __shfl_xor(li, off, 64);
                bool tk = (ov > lv) || (ov == lv && oi < li);
                lv = tk ? ov : lv;
                li = tk ? oi : li;
            }
            wv[e] = lv; wi[e] = li;
            bool pop = (topv[j][0] == lv) && (topi[j][0] == li);
#pragma unroll
            for (int t = 0; t < TOPK - 1; ++t) {
                topv[j][t] = pop ? topv[j][t + 1] : topv[j][t];
                topi[j][t] = pop ? topi[j][t + 1] : topi[j][t];
            }
            topv[j][TOPK - 1] = pop ? -1e30f : topv[j][TOPK - 1];
            topi[j][TOPK - 1] = pop ? 0x7FFFFFFF : topi[j][TOPK - 1];
        }

        float mx = wv[0] * 0.125f;
        float ex[TOPK]; float Z = 0.f;
#pragma unroll
        for (int e = 0; e < TOPK; ++e) { ex[e] = expf(wv[e] * 0.125f - mx); Z += ex[e]; }
        float invZ = 1.0f / Z;

        float4 a0 = {0.f, 0.f, 0.f, 0.f}, a1 = {0.f, 0.f, 0.f, 0.f};
#pragma unroll
        for (int e = 0; e < TOPK; ++e) {
            const float4* sp = (const float4*)(states + ((long)b * NN + wi[e]) * DD);
            float4 s0 = sp[mg];
            float4 s1 = sp[mg + 32];
            float we = ex[e] * invZ;
            a0.x = fmaf(we, s0.x, a0.x); a0.y = fmaf(we, s0.y, a0.y);
            a0.z = fmaf(we, s0.z, a0.z); a0.w = fmaf(we, s0.w, a0.w);
            a1.x = fmaf(we, s1.x, a1.x); a1.y = fmaf(we, s1.y, a1.y);
            a1.z = fmaf(we, s1.z, a1.z); a1.w = fmaf(we, s1.w, a1.w);
        }
        float4* op = (float4*)(incoming + ((long)b * NN + n0 + rr) * DD);
        op[mg] = a0;
        op[mg + 32] = a1;
    }
}

// ---------------------------------------------------------------------------
// K3: sim = pn pn^T via bf16 MFMA (selection only; values stay fp32).
// A = 16 block rows (frags in regs), B = 128-row m-tiles staged via
// global_load_lds, XOR chunk swizzle (chunk^(row&7), 8x16B chunks/row).
// ---------------------------------------------------------------------------
#define CAP 64
__global__ __launch_bounds__(256, 4) void k_coal(
    const unsigned short* __restrict__ PNb, const float* __restrict__ incoming,
    float* __restrict__ outs)
{
    __shared__ unsigned short Asb[16 * 64];    // 2KB
    __shared__ unsigned short Bsb[128 * 64];   // 16KB
    __shared__ int cnt[16];
    __shared__ unsigned short lst[16][CAP];    // 2KB

    const int tid = threadIdx.x;
    const int lane = tid & 63;
    const int wid = tid >> 6;
    const int b  = blockIdx.x >> 8;
    const int n0 = (blockIdx.x & 255) << 4;
    const int r = lane & 15, g = lane >> 4;

    if (tid < 16) cnt[tid] = 0;

    // stage A tile (16 rows x 8 chunks), swizzled source, linear dest
    {
        const unsigned short* ab = PNb + ((long)b * NN + n0) * PP;
        if (tid < 128) {
            int row = tid >> 3, c = tid & 7;
            int cs = c ^ (row & 7);
            gload_lds16b(ab + row * PP + cs * 8, Asb + (wid * 64) * 8);
        }
    }
    __syncthreads();

    // A fragments (2 K-steps), kept in registers for the whole kernel
    s8v afr[2];
#pragma unroll
    for (int s = 0; s < 2; ++s) {
        int c = s * 4 + g;
        int cd = c ^ (r & 7);
        afr[s] = *(const s8v*)(Asb + r * 64 + cd * 8);
    }

    for (int mt = 0; mt < NN / 128; ++mt) {
        const int m0 = mt << 7;
        __syncthreads();
        {
            const unsigned short* bb = PNb + ((long)b * NN + m0) * PP;
#pragma unroll
            for (int t = 0; t < 4; ++t) {
                int q = t * 256 + tid;
                int row = q >> 3, c = q & 7;
                int cs = c ^ (row & 7);
                gload_lds16b(bb + row * PP + cs * 8,
                             Bsb + (t * 256 + wid * 64) * 8);
            }
        }
        __syncthreads();

#pragma unroll
        for (int t = 0; t < 2; ++t) {
            const int mrow = (wid * 2 + t) * 16 + r;
            f4v acc = {0.f, 0.f, 0.f, 0.f};
#pragma unroll
            for (int s = 0; s < 2; ++s) {
                int c = s * 4 + g;
                int cd = c ^ (mrow & 7);
                s8v bfr = *(const s8v*)(Bsb + mrow * 64 + cd * 8);
                acc = __builtin_amdgcn_mfma_f32_16x16x32_bf16(afr[s], bfr, acc, 0, 0, 0);
            }
            // C: row(q) = g*4+reg, col(m) = r
#pragma unroll
            for (int rr2 = 0; rr2 < 4; ++rr2) {
                if (acc[rr2] > 0.7f) {
                    int qrow = g * 4 + rr2;
                    int m = m0 + (wid * 2 + t) * 16 + r;
                    int pos = atomicAdd(&cnt[qrow], 1);
                    if (pos < CAP) lst[qrow][pos] = (unsigned short)m;
                }
            }
        }
    }
    __syncthreads();

    const int w = tid >> 6;
    for (int rr = w * 4; rr < w * 4 + 4; ++rr) {
        int c = cnt[rr];
        float inv = 1.0f / ((float)c + 1e-8f);
        int cc = (c < CAP) ? c : CAP;
        float ax = 0.f, ay = 0.f, az = 0.f, aw = 0.f;
        for (int i = 0; i < cc; ++i) {
            const float4* ip = (const float4*)(incoming + ((long)b * NN + lst[rr][i]) * DD);
            float4 v = ip[lane];
            ax += v.x; ay += v.y; az += v.z; aw += v.w;
        }
        const float4* self4 = (const float4*)(incoming + ((long)b * NN + n0 + rr) * DD);
        float4 sv = self4[lane];
        float4 o;
        o.x = 0.8f * sv.x + 0.2f * inv * ax;
        o.y = 0.8f * sv.y + 0.2f * inv * ay;
        o.z = 0.8f * sv.z + 0.2f * inv * az;
        o.w = 0.8f * sv.w + 0.2f * inv * aw;
        ((float4*)(outs + ((long)b * NN + n0 + rr) * DD))[lane] = o;
    }
}

// ---------------------------------------------------------------------------
// K4: y = outs@Wh via bf16 MFMA; fused tanh/bind/decay/cosine epilogue.
// 512 thr, 16 rows/block. 2 h-halves x 4 K-slabs(64); B=Whb_t staged 64KB.
// ---------------------------------------------------------------------------
__global__ __launch_bounds__(512, 4) void k_mem(
    const float* __restrict__ outs, const unsigned short* __restrict__ Whb,
    const float* __restrict__ bh, const float* __restrict__ keys,
    const float* __restrict__ pos_codes, const int* __restrict__ stepp,
    const float* __restrict__ mem,
    float* __restrict__ epi_out, float* __restrict__ sim_out)
{
    __shared__ unsigned short Ab[16 * 256];    // 8KB  bf16 outs rows, 32 chunks/row
    __shared__ unsigned short Bb[512 * 64];    // 64KB Whb_t slab [512 h][64 k]
    __shared__ float red[8][16][3];

    const int tid = threadIdx.x;
    const int lane = tid & 63;
    const int wid = tid >> 6;
    const long row0 = (long)blockIdx.x * 16;
    const int r = lane & 15, g = lane >> 4;

    // convert A: outs rows -> bf16 LDS, chunk-swizzled (c^(row&7), low 3 bits)
    {
        int row = tid >> 5, c = tid & 31;
        const float4* src = (const float4*)(outs + (row0 + row) * DD + c * 8);
        float4 x0 = src[0], x1 = src[1];
        s8v h8;
        h8[0] = (short)f2b(x0.x); h8[1] = (short)f2b(x0.y);
        h8[2] = (short)f2b(x0.z); h8[3] = (short)f2b(x0.w);
        h8[4] = (short)f2b(x1.x); h8[5] = (short)f2b(x1.y);
        h8[6] = (short)f2b(x1.z); h8[7] = (short)f2b(x1.w);
        int cd = c ^ (row & 7);
        *(s8v*)(Ab + row * 256 + cd * 8) = h8;
    }

    const int step = stepp[0];
    const int prow = ((step % NCC) + NCC) % NCC;
    float snp[4], snn[4], spp[4];
#pragma unroll
    for (int j = 0; j < 4; ++j) { snp[j] = 0.f; snn[j] = 0.f; spp[j] = 0.f; }

    for (int half = 0; half < 2; ++half) {
        f4v acc[4];
#pragma unroll
        for (int t = 0; t < 4; ++t) acc[t] = (f4v){0.f, 0.f, 0.f, 0.f};

        for (int ks = 0; ks < 4; ++ks) {
            __syncthreads();
            {
#pragma unroll
                for (int t = 0; t < 8; ++t) {
                    int q = t * 512 + tid;
                    int row = q >> 3, c = q & 7;
                    int cs = c ^ (row & 7);
                    gload_lds16b(Whb + (long)(half * 512 + row) * DD + ks * 64 + cs * 8,
                                 Bb + (t * 512 + wid * 64) * 8);
                }
            }
            __syncthreads();

            s8v af[2];
#pragma unroll
            for (int s = 0; s < 2; ++s) {
                int c = ks * 8 + s * 4 + g;
                int cd = c ^ (r & 7);
                af[s] = *(const s8v*)(Ab + r * 256 + cd * 8);
            }
#pragma unroll
            for (int t = 0; t < 4; ++t) {
                const int hrow = (wid * 4 + t) * 16 + r;
#pragma unroll
                for (int s = 0; s < 2; ++s) {
                    int c = s * 4 + g;
                    int cd = c ^ (hrow & 7);
                    s8v bf = *(const s8v*)(Bb + hrow * 64 + cd * 8);
                    acc[t] = __builtin_amdgcn_mfma_f32_16x16x32_bf16(af[s], bf, acc[t], 0, 0, 0);
                }
            }
        }

        // epilogue for this h-half; C: row(q)=g*4+reg, col(h)=r
#pragma unroll
        for (int t = 0; t < 4; ++t) {
            int h = half * 512 + (wid * 4 + t) * 16 + r;
            float ps = pos_codes[(long)prow * HH + h];
            float bb_ = bh[h];
#pragma unroll
            for (int rr2 = 0; rr2 < 4; ++rr2) {
                long row = row0 + g * 4 + rr2;
                int n = (int)(row & (NN - 1));
                float y = acc[t][rr2] + bb_;
                float e = __expf(6.0f * y);
                float hd = 1.0f - __fdividef(2.0f, e + 1.0f);   // tanh(3y)
                float pe = hd * keys[(long)n * HH + h];
                float ne = 0.95f * mem[row * HH + h] + 0.05f * (pe * ps);
                epi_out[row * HH + h] = ne;
                snp[rr2] = fmaf(ne, pe, snp[rr2]);
                snn[rr2] = fmaf(ne, ne, snn[rr2]);
                spp[rr2] = fmaf(pe, pe, spp[rr2]);
            }
        }
    }

    // reduce over the 16 lanes of each quarter-wave group (same 4 rows)
#pragma unroll
    for (int rr2 = 0; rr2 < 4; ++rr2) {
#pragma unroll
        for (int off = 1; off <= 8; off <<= 1) {
            snp[rr2] += __shfl_xor(snp[rr2], off, 64);
            snn[rr2] += __shfl_xor(snn[rr2], off, 64);
            spp[rr2] += __shfl_xor(spp[rr2], off, 64);
        }
    }
    if (r == 0) {
#pragma unroll
        for (int rr2 = 0; rr2 < 4; ++rr2) {
            red[wid][g * 4 + rr2][0] = snp[rr2];
            red[wid][g * 4 + rr2][1] = snn[rr2];
            red[wid][g * 4 + rr2][2] = spp[rr2];
        }
    }
    __syncthreads();
    if (tid < 16) {
        float dot = 0.f, nn = 0.f, pp = 0.f;
#pragma unroll
        for (int wv = 0; wv < 8; ++wv) {
            dot += red[wv][tid][0]; nn += red[wv][tid][1]; pp += red[wv][tid][2];
        }
        float na = fmaxf(sqrtf(nn), 1e-8f);
        float nb = fmaxf(sqrtf(pp), 1e-8f);
        sim_out[row0 + tid] = dot / (na * nb);
    }
}

// ---------------------------------------------------------------------------
extern "C" void kernel_launch(void* const* d_in, const int* in_sizes, int n_in,
                              void* d_out, int out_size, void* d_ws, size_t ws_size,
                              hipStream_t stream)
{
    const float* states  = (const float*)d_in[0];
    const float* actions = (const float*)d_in[1];
    const float* mem     = (const float*)d_in[2];
    const float* Wq = (const float*)d_in[3];
    const float* bq = (const float*)d_in[4];
    const float* Wk = (const float*)d_in[5];
    const float* bk = (const float*)d_in[6];
    const float* Wc = (const float*)d_in[7];
    const float* bc = (const float*)d_in[8];
    const float* Wh = (const float*)d_in[9];
    const float* bh = (const float*)d_in[10];
    const float* keys = (const float*)d_in[11];
    const float* pos  = (const float*)d_in[12];
    const int*   step = (const int*)d_in[13];

    float* ws = (float*)d_ws;
    float* Q        = ws;                    // 1,048,576 floats
    float* K        = ws + 1048576;          // 1,048,576 floats
    unsigned short* PNb = (unsigned short*)(ws + 2097152);   // 1,048,576 ushorts (2MB)
    unsigned short* Whb = PNb + 1048576;     // 262,144 ushorts (0.5MB), within PN region
    float* incoming = ws + 3145728;          // 4,194,304 floats

    float* outs = (float*)d_out;                       // B*N*D
    float* epi  = outs + (long)BB * NN * DD;           // B*N*H
    float* simo = epi + (long)BB * NN * HH;            // B*N

    hipLaunchKernelGGL(k_proj, dim3(BB * NN / 16), dim3(256), 0, stream,
                       actions, Wq, bq, Wk, bk, Wc, bc, Wh, Q, K, PNb, Whb);
    hipLaunchKernelGGL(k_topk, dim3(BB * (NN / 16)), dim3(256), 0, stream,
                       Q, K, states, incoming);
    hipLaunchKernelGGL(k_coal, dim3(BB * (NN / 16)), dim3(256), 0, stream,
                       PNb, incoming, outs);
    hipLaunchKernelGGL(k_mem, dim3(BB * NN / 16), dim3(512), 0, stream,
                       outs, Whb, bh, keys, pos, step, mem, epi, simo);
}

// Round 10
// 224.506 us; speedup vs baseline: 2.9831x; 1.5621x over previous
//
#include <hip/hip_runtime.h>

#define BB 4
#define NN 4096
#define DD 256
#define PP 64
#define HH 1024
#define NCC 256
#define TOPK 8
#define CAP2 128

typedef __attribute__((ext_vector_type(8))) short s8v;   // 8 bf16
typedef __attribute__((ext_vector_type(4))) float f4v;   // 4 f32

__device__ __forceinline__ void gload_lds16(const float* g, float* l) {
    __builtin_amdgcn_global_load_lds(
        (const __attribute__((address_space(1))) void*)g,
        (__attribute__((address_space(3))) void*)l, 16, 0, 0);
}
__device__ __forceinline__ void gload_lds16b(const unsigned short* g, unsigned short* l) {
    __builtin_amdgcn_global_load_lds(
        (const __attribute__((address_space(1))) void*)g,
        (__attribute__((address_space(3))) void*)l, 16, 0, 0);
}
__device__ __forceinline__ unsigned short f2b(float f) {   // RNE f32->bf16
    unsigned int u = __float_as_uint(f);
    unsigned int r = (u + 0x7FFFu + ((u >> 16) & 1u)) >> 16;
    return (unsigned short)r;
}

// ---------------------------------------------------------------------------
// K0: G = Wk^T Wk  (64x64). block i computes G[i][*].
// ---------------------------------------------------------------------------
__global__ __launch_bounds__(64) void k_gram(const float* __restrict__ Wk,
                                             float* __restrict__ G)
{
    int i = blockIdx.x, j = threadIdx.x;
    float s = 0.f;
#pragma unroll 8
    for (int d = 0; d < DD; ++d)
        s = fmaf(Wk[d * PP + i], Wk[d * PP + j], s);
    G[i * PP + j] = s;
}

// ---------------------------------------------------------------------------
// K1: Q,K (fp32) + Kb (bf16) + pn (bf16) + Whb_t (bf16) + per-row threshold
// T = q.bk + 2.25*sqrt(q^T G q)  (exact Gaussian score model).
// ---------------------------------------------------------------------------
__global__ __launch_bounds__(256) void k_proj(
    const float* __restrict__ act,
    const float* __restrict__ Wq, const float* __restrict__ bq,
    const float* __restrict__ Wk, const float* __restrict__ bk,
    const float* __restrict__ Wc, const float* __restrict__ bc,
    const float* __restrict__ Wh, const float* __restrict__ G,
    float* __restrict__ Qo, float* __restrict__ Ko,
    unsigned short* __restrict__ PNb, unsigned short* __restrict__ Whb,
    unsigned short* __restrict__ Kbo, float* __restrict__ Tg)
{
    __shared__ float As[16][DD];   // 16KB; first 64 cols reused as Qs2 later
    __shared__ float Ps[16][PP];   // 4KB
    const int tid = threadIdx.x;
    const long row0 = (long)blockIdx.x * 16;

    {
        const float4* g4 = (const float4*)(act + row0 * DD);
        float4* s4 = (float4*)(&As[0][0]);
#pragma unroll
        for (int i = 0; i < 4; ++i) s4[tid + i * 256] = g4[tid + i * 256];
    }
    {
        int h = blockIdx.x;                      // grid == HH
        Whb[(long)h * DD + tid] = f2b(Wh[(long)tid * HH + h]);
    }
    __syncthreads();

    const int col = tid & 63;
    const int rg  = tid >> 6;   // 0..3 -> rows rg*4+j
    float aq[4], ak[4], ac[4];
#pragma unroll
    for (int j = 0; j < 4; ++j) { aq[j] = bq[col]; ak[j] = bk[col]; ac[j] = bc[col]; }

    for (int d = 0; d < DD; ++d) {
        float wq = Wq[d * PP + col];
        float wk = Wk[d * PP + col];
        float wc = Wc[d * PP + col];
#pragma unroll
        for (int j = 0; j < 4; ++j) {
            float a = As[rg * 4 + j][d];
            aq[j] = fmaf(a, wq, aq[j]);
            ak[j] = fmaf(a, wk, ak[j]);
            ac[j] = fmaf(a, wc, ac[j]);
        }
    }
    __syncthreads();   // all waves done reading As before reuse

#pragma unroll
    for (int j = 0; j < 4; ++j) {
        long r = row0 + rg * 4 + j;
        Qo[r * PP + col] = aq[j];
        Ko[r * PP + col] = ak[j];
        Kbo[r * PP + col] = f2b(ak[j]);
        Ps[rg * 4 + j][col] = ac[j];
        As[rg * 4 + j][col] = aq[j];   // Qs2: q rows for the T phase
    }
    __syncthreads();

    const int w = tid >> 6;
    const int lane = tid & 63;
#pragma unroll
    for (int j = 0; j < 4; ++j) {
        int r = w * 4 + j;
        float v = Ps[r][lane];
        float ss = v * v;
#pragma unroll
        for (int off = 32; off >= 1; off >>= 1) ss += __shfl_xor(ss, off, 64);
        float nrm = fmaxf(sqrtf(ss), 1e-12f);
        PNb[(row0 + r) * PP + lane] = f2b(v / nrm);
    }

    // T phase: sigma^2 = q^T G q (G symmetric -> read G[c'][lane], coalesced)
#pragma unroll
    for (int j = 0; j < 4; ++j) {
        int r = w * 4 + j;
        float qc = As[r][lane];
        float gq = 0.f;
#pragma unroll 8
        for (int c2 = 0; c2 < 64; ++c2)
            gq = fmaf(G[c2 * PP + lane], As[r][c2], gq);
        float s2 = qc * gq;
        float mu = qc * bk[lane];
#pragma unroll
        for (int off = 32; off >= 1; off >>= 1) {
            s2 += __shfl_xor(s2, off, 64);
            mu += __shfl_xor(mu, off, 64);
        }
        if (lane == 0)
            Tg[row0 + r] = mu + 2.25f * sqrtf(fmaxf(s2, 0.f));
    }
}

// ---------------------------------------------------------------------------
// K2 v3: approx scores via bf16 MFMA -> threshold-collect -> exact fp32
// rescore of the <=128 survivors -> top-8 -> softmax -> gather.
// 16 rows/block, grid 1024, ~24KB LDS.
// ---------------------------------------------------------------------------
__device__ __forceinline__ float dot64(const float* q, const float* k) {
    float s = 0.f;
    const float4* k4 = (const float4*)k;
#pragma unroll
    for (int t = 0; t < 16; ++t) {
        float4 kv = k4[t];
        float4 qv = *(const float4*)(q + t * 4);
        s = fmaf(qv.x, kv.x, s);
        s = fmaf(qv.y, kv.y, s);
        s = fmaf(qv.z, kv.z, s);
        s = fmaf(qv.w, kv.w, s);
    }
    return s;
}

__global__ __launch_bounds__(256, 4) void k_topk(
    const float* __restrict__ Q, const float* __restrict__ K,
    const unsigned short* __restrict__ Kb, const float* __restrict__ Tg,
    const float* __restrict__ states, float* __restrict__ incoming)
{
    __shared__ float Qsf[16][64];              // 4KB fp32 Q rows
    __shared__ unsigned short Bsb[128 * 64];   // 16KB bf16 K tile (swizzled)
    __shared__ int cnt[16];
    __shared__ unsigned short lst[16][CAP2];   // 4KB

    const int tid = threadIdx.x;
    const int lane = tid & 63;
    const int wid = tid >> 6;
    const int b  = blockIdx.x >> 8;
    const int n0 = (blockIdx.x & 255) << 4;
    const int r = lane & 15, g = lane >> 4;

    if (tid < 16) cnt[tid] = 0;
    ((float4*)&Qsf[0][0])[tid] = ((const float4*)(Q + ((long)b * NN + n0) * PP))[tid];
    __syncthreads();

    // A fragments: lane (r,g) holds Q[row=r][k=(s*4+g)*8 .. +7], bf16
    s8v afr[2];
#pragma unroll
    for (int s = 0; s < 2; ++s) {
        int c = s * 4 + g;
        float4 x0 = *(const float4*)(&Qsf[r][c * 8]);
        float4 x1 = *(const float4*)(&Qsf[r][c * 8 + 4]);
        s8v h;
        h[0] = (short)f2b(x0.x); h[1] = (short)f2b(x0.y);
        h[2] = (short)f2b(x0.z); h[3] = (short)f2b(x0.w);
        h[4] = (short)f2b(x1.x); h[5] = (short)f2b(x1.y);
        h[6] = (short)f2b(x1.z); h[7] = (short)f2b(x1.w);
        afr[s] = h;
    }
    float tT[4];
#pragma unroll
    for (int rr2 = 0; rr2 < 4; ++rr2)
        tT[rr2] = Tg[(long)b * NN + n0 + g * 4 + rr2];

    for (int mt = 0; mt < NN / 128; ++mt) {
        const int m0 = mt << 7;
        __syncthreads();
        {
#pragma unroll
            for (int t = 0; t < 4; ++t) {
                int q = t * 256 + tid;
                int row = q >> 3, c = q & 7;
                int cs = c ^ (row & 7);
                gload_lds16b(Kb + ((long)(b * NN + m0 + row)) * PP + cs * 8,
                             Bsb + (t * 256 + wid * 64) * 8);
            }
        }
        __syncthreads();

#pragma unroll
        for (int t = 0; t < 2; ++t) {
            const int mrow = (wid * 2 + t) * 16 + r;
            f4v acc = {0.f, 0.f, 0.f, 0.f};
#pragma unroll
            for (int s = 0; s < 2; ++s) {
                int c = s * 4 + g;
                int cd = c ^ (mrow & 7);
                s8v bfr = *(const s8v*)(Bsb + mrow * 64 + cd * 8);
                acc = __builtin_amdgcn_mfma_f32_16x16x32_bf16(afr[s], bfr, acc, 0, 0, 0);
            }
            // C layout: row(q) = g*4+reg, col(m within tile) = r
#pragma unroll
            for (int rr2 = 0; rr2 < 4; ++rr2) {
                if (acc[rr2] >= tT[rr2]) {
                    int qrow = g * 4 + rr2;
                    int pos = atomicAdd(&cnt[qrow], 1);
                    if (pos < CAP2)
                        lst[qrow][pos] = (unsigned short)(m0 + (wid * 2 + t) * 16 + r);
                }
            }
        }
    }
    __syncthreads();

    // epilogue: wave wid handles rows wid*4 .. wid*4+3
    for (int rr = wid * 4; rr < wid * 4 + 4; ++rr) {
        int c = cnt[rr]; if (c > CAP2) c = CAP2;
        float sc0 = -1e30f, sc1 = -1e30f;
        int i0 = 0x7FFFFFFF, i1 = 0x7FFFFFFF;
        if (lane < c) {
            i0 = lst[rr][lane];
            sc0 = dot64(&Qsf[rr][0], K + ((long)b * NN + i0) * PP);
        }
        if (lane + 64 < c) {
            i1 = lst[rr][lane + 64];
            sc1 = dot64(&Qsf[rr][0], K + ((long)b * NN + i1) * PP);
        }
        float wv[TOPK]; int wi[TOPK];
#pragma unroll
        for (int e = 0; e < TOPK; ++e) {
            bool p0 = (sc0 > sc1) || (sc0 == sc1 && i0 < i1);
            float lv = p0 ? sc0 : sc1;
            int   li = p0 ? i0 : i1;
#pragma unroll
            for (int off = 32; off >= 1; off >>= 1) {
                float ov = __shfl_xor(lv, off, 64);
                int   oi = __shfl_xor(li, off, 64);
                bool tk = (ov > lv) || (ov == lv && oi < li);
                lv = tk ? ov : lv;
                li = tk ? oi : li;
            }
            wv[e] = lv; wi[e] = li;
            if (sc0 == lv && i0 == li)      { sc0 = -1e30f; i0 = 0x7FFFFFFF; }
            else if (sc1 == lv && i1 == li) { sc1 = -1e30f; i1 = 0x7FFFFFFF; }
        }

        float mx = wv[0] * 0.125f;
        float ex[TOPK]; float Z = 0.f;
#pragma unroll
        for (int e = 0; e < TOPK; ++e) { ex[e] = expf(wv[e] * 0.125f - mx); Z += ex[e]; }
        float invZ = 1.0f / Z;

        float4 a0 = {0.f, 0.f, 0.f, 0.f};
#pragma unroll
        for (int e = 0; e < TOPK; ++e) {
            int gi = wi[e] & (NN - 1);   // safe addr; weight ~0 for sentinels
            float4 sv = ((const float4*)(states + ((long)b * NN + gi) * DD))[lane];
            float we = ex[e] * invZ;
            a0.x = fmaf(we, sv.x, a0.x); a0.y = fmaf(we, sv.y, a0.y);
            a0.z = fmaf(we, sv.z, a0.z); a0.w = fmaf(we, sv.w, a0.w);
        }
        ((float4*)(incoming + ((long)b * NN + n0 + rr) * DD))[lane] = a0;
    }
}

// ---------------------------------------------------------------------------
// K3: sim = pn pn^T via bf16 MFMA (selection only). Unchanged from r9.
// ---------------------------------------------------------------------------
#define CAP 64
__global__ __launch_bounds__(256, 4) void k_coal(
    const unsigned short* __restrict__ PNb, const float* __restrict__ incoming,
    float* __restrict__ outs)
{
    __shared__ unsigned short Asb[16 * 64];    // 2KB
    __shared__ unsigned short Bsb[128 * 64];   // 16KB
    __shared__ int cnt[16];
    __shared__ unsigned short lst[16][CAP];    // 2KB

    const int tid = threadIdx.x;
    const int lane = tid & 63;
    const int wid = tid >> 6;
    const int b  = blockIdx.x >> 8;
    const int n0 = (blockIdx.x & 255) << 4;
    const int r = lane & 15, g = lane >> 4;

    if (tid < 16) cnt[tid] = 0;

    {
        const unsigned short* ab = PNb + ((long)b * NN + n0) * PP;
        if (tid < 128) {
            int row = tid >> 3, c = tid & 7;
            int cs = c ^ (row & 7);
            gload_lds16b(ab + row * PP + cs * 8, Asb + (wid * 64) * 8);
        }
    }
    __syncthreads();

    s8v afr[2];
#pragma unroll
    for (int s = 0; s < 2; ++s) {
        int c = s * 4 + g;
        int cd = c ^ (r & 7);
        afr[s] = *(const s8v*)(Asb + r * 64 + cd * 8);
    }

    for (int mt = 0; mt < NN / 128; ++mt) {
        const int m0 = mt << 7;
        __syncthreads();
        {
            const unsigned short* bb = PNb + ((long)b * NN + m0) * PP;
#pragma unroll
            for (int t = 0; t < 4; ++t) {
                int q = t * 256 + tid;
                int row = q >> 3, c = q & 7;
                int cs = c ^ (row & 7);
                gload_lds16b(bb + row * PP + cs * 8,
                             Bsb + (t * 256 + wid * 64) * 8);
            }
        }
        __syncthreads();

#pragma unroll
        for (int t = 0; t < 2; ++t) {
            const int mrow = (wid * 2 + t) * 16 + r;
            f4v acc = {0.f, 0.f, 0.f, 0.f};
#pragma unroll
            for (int s = 0; s < 2; ++s) {
                int c = s * 4 + g;
                int cd = c ^ (mrow & 7);
                s8v bfr = *(const s8v*)(Bsb + mrow * 64 + cd * 8);
                acc = __builtin_amdgcn_mfma_f32_16x16x32_bf16(afr[s], bfr, acc, 0, 0, 0);
            }
#pragma unroll
            for (int rr2 = 0; rr2 < 4; ++rr2) {
                if (acc[rr2] > 0.7f) {
                    int qrow = g * 4 + rr2;
                    int m = m0 + (wid * 2 + t) * 16 + r;
                    int pos = atomicAdd(&cnt[qrow], 1);
                    if (pos < CAP) lst[qrow][pos] = (unsigned short)m;
                }
            }
        }
    }
    __syncthreads();

    const int w = tid >> 6;
    for (int rr = w * 4; rr < w * 4 + 4; ++rr) {
        int c = cnt[rr];
        float inv = 1.0f / ((float)c + 1e-8f);
        int cc = (c < CAP) ? c : CAP;
        float ax = 0.f, ay = 0.f, az = 0.f, aw = 0.f;
        for (int i = 0; i < cc; ++i) {
            const float4* ip = (const float4*)(incoming + ((long)b * NN + lst[rr][i]) * DD);
            float4 v = ip[lane];
            ax += v.x; ay += v.y; az += v.z; aw += v.w;
        }
        const float4* self4 = (const float4*)(incoming + ((long)b * NN + n0 + rr) * DD);
        float4 sv = self4[lane];
        float4 o;
        o.x = 0.8f * sv.x + 0.2f * inv * ax;
        o.y = 0.8f * sv.y + 0.2f * inv * ay;
        o.z = 0.8f * sv.z + 0.2f * inv * az;
        o.w = 0.8f * sv.w + 0.2f * inv * aw;
        ((float4*)(outs + ((long)b * NN + n0 + rr) * DD))[lane] = o;
    }
}

// ---------------------------------------------------------------------------
// K4: y = outs@Wh via bf16 MFMA; fused tanh/bind/decay/cosine. Unchanged.
// ---------------------------------------------------------------------------
__global__ __launch_bounds__(512, 4) void k_mem(
    const float* __restrict__ outs, const unsigned short* __restrict__ Whb,
    const float* __restrict__ bh, const float* __restrict__ keys,
    const float* __restrict__ pos_codes, const int* __restrict__ stepp,
    const float* __restrict__ mem,
    float* __restrict__ epi_out, float* __restrict__ sim_out)
{
    __shared__ unsigned short Ab[16 * 256];    // 8KB
    __shared__ unsigned short Bb[512 * 64];    // 64KB
    __shared__ float red[8][16][3];

    const int tid = threadIdx.x;
    const int lane = tid & 63;
    const int wid = tid >> 6;
    const long row0 = (long)blockIdx.x * 16;
    const int r = lane & 15, g = lane >> 4;

    {
        int row = tid >> 5, c = tid & 31;
        const float4* src = (const float4*)(outs + (row0 + row) * DD + c * 8);
        float4 x0 = src[0], x1 = src[1];
        s8v h8;
        h8[0] = (short)f2b(x0.x); h8[1] = (short)f2b(x0.y);
        h8[2] = (short)f2b(x0.z); h8[3] = (short)f2b(x0.w);
        h8[4] = (short)f2b(x1.x); h8[5] = (short)f2b(x1.y);
        h8[6] = (short)f2b(x1.z); h8[7] = (short)f2b(x1.w);
        int cd = c ^ (row & 7);
        *(s8v*)(Ab + row * 256 + cd * 8) = h8;
    }

    const int step = stepp[0];
    const int prow = ((step % NCC) + NCC) % NCC;
    float snp[4], snn[4], spp[4];
#pragma unroll
    for (int j = 0; j < 4; ++j) { snp[j] = 0.f; snn[j] = 0.f; spp[j] = 0.f; }

    for (int half = 0; half < 2; ++half) {
        f4v acc[4];
#pragma unroll
        for (int t = 0; t < 4; ++t) acc[t] = (f4v){0.f, 0.f, 0.f, 0.f};

        for (int ks = 0; ks < 4; ++ks) {
            __syncthreads();
            {
#pragma unroll
                for (int t = 0; t < 8; ++t) {
                    int q = t * 512 + tid;
                    int row = q >> 3, c = q & 7;
                    int cs = c ^ (row & 7);
                    gload_lds16b(Whb + (long)(half * 512 + row) * DD + ks * 64 + cs * 8,
                                 Bb + (t * 512 + wid * 64) * 8);
                }
            }
            __syncthreads();

            s8v af[2];
#pragma unroll
            for (int s = 0; s < 2; ++s) {
                int c = ks * 8 + s * 4 + g;
                int cd = c ^ (r & 7);
                af[s] = *(const s8v*)(Ab + r * 256 + cd * 8);
            }
#pragma unroll
            for (int t = 0; t < 4; ++t) {
                const int hrow = (wid * 4 + t) * 16 + r;
#pragma unroll
                for (int s = 0; s < 2; ++s) {
                    int c = s * 4 + g;
                    int cd = c ^ (hrow & 7);
                    s8v bf = *(const s8v*)(Bb + hrow * 64 + cd * 8);
                    acc[t] = __builtin_amdgcn_mfma_f32_16x16x32_bf16(af[s], bf, acc[t], 0, 0, 0);
                }
            }
        }

#pragma unroll
        for (int t = 0; t < 4; ++t) {
            int h = half * 512 + (wid * 4 + t) * 16 + r;
            float ps = pos_codes[(long)prow * HH + h];
            float bb_ = bh[h];
#pragma unroll
            for (int rr2 = 0; rr2 < 4; ++rr2) {
                long row = row0 + g * 4 + rr2;
                int n = (int)(row & (NN - 1));
                float y = acc[t][rr2] + bb_;
                float e = __expf(6.0f * y);
                float hd = 1.0f - __fdividef(2.0f, e + 1.0f);
                float pe = hd * keys[(long)n * HH + h];
                float ne = 0.95f * mem[row * HH + h] + 0.05f * (pe * ps);
                epi_out[row * HH + h] = ne;
                snp[rr2] = fmaf(ne, pe, snp[rr2]);
                snn[rr2] = fmaf(ne, ne, snn[rr2]);
                spp[rr2] = fmaf(pe, pe, spp[rr2]);
            }
        }
    }

#pragma unroll
    for (int rr2 = 0; rr2 < 4; ++rr2) {
#pragma unroll
        for (int off = 1; off <= 8; off <<= 1) {
            snp[rr2] += __shfl_xor(snp[rr2], off, 64);
            snn[rr2] += __shfl_xor(snn[rr2], off, 64);
            spp[rr2] += __shfl_xor(spp[rr2], off, 64);
        }
    }
    if (r == 0) {
#pragma unroll
        for (int rr2 = 0; rr2 < 4; ++rr2) {
            red[wid][g * 4 + rr2][0] = snp[rr2];
            red[wid][g * 4 + rr2][1] = snn[rr2];
            red[wid][g * 4 + rr2][2] = spp[rr2];
        }
    }
    __syncthreads();
    if (tid < 16) {
        float dot = 0.f, nn = 0.f, pp = 0.f;
#pragma unroll
        for (int wv = 0; wv < 8; ++wv) {
            dot += red[wv][tid][0]; nn += red[wv][tid][1]; pp += red[wv][tid][2];
        }
        float na = fmaxf(sqrtf(nn), 1e-8f);
        float nb = fmaxf(sqrtf(pp), 1e-8f);
        sim_out[row0 + tid] = dot / (na * nb);
    }
}

// ---------------------------------------------------------------------------
extern "C" void kernel_launch(void* const* d_in, const int* in_sizes, int n_in,
                              void* d_out, int out_size, void* d_ws, size_t ws_size,
                              hipStream_t stream)
{
    const float* states  = (const float*)d_in[0];
    const float* actions = (const float*)d_in[1];
    const float* mem     = (const float*)d_in[2];
    const float* Wq = (const float*)d_in[3];
    const float* bq = (const float*)d_in[4];
    const float* Wk = (const float*)d_in[5];
    const float* bk = (const float*)d_in[6];
    const float* Wc = (const float*)d_in[7];
    const float* bc = (const float*)d_in[8];
    const float* Wh = (const float*)d_in[9];
    const float* bh = (const float*)d_in[10];
    const float* keys = (const float*)d_in[11];
    const float* pos  = (const float*)d_in[12];
    const int*   step = (const int*)d_in[13];

    float* ws = (float*)d_ws;
    float* Q        = ws;                                    // 1,048,576 f
    float* K        = ws + 1048576;                          // 1,048,576 f
    unsigned short* PNb = (unsigned short*)(ws + 2097152);   // 1M shorts
    unsigned short* Whb = PNb + 1048576;                     // 256K shorts
    float* incoming = ws + 3145728;                          // 4,194,304 f
    unsigned short* Kb = (unsigned short*)(ws + 7340032);    // 1M shorts (2MB)
    float* Tg       = ws + 7340032 + 524288;                 // 16,384 f
    float* G        = Tg + 16384;                            // 4,096 f

    float* outs = (float*)d_out;                       // B*N*D
    float* epi  = outs + (long)BB * NN * DD;           // B*N*H
    float* simo = epi + (long)BB * NN * HH;            // B*N

    hipLaunchKernelGGL(k_gram, dim3(64), dim3(64), 0, stream, Wk, G);
    hipLaunchKernelGGL(k_proj, dim3(BB * NN / 16), dim3(256), 0, stream,
                       actions, Wq, bq, Wk, bk, Wc, bc, Wh, G,
                       Q, K, PNb, Whb, Kb, Tg);
    hipLaunchKernelGGL(k_topk, dim3(BB * (NN / 16)), dim3(256), 0, stream,
                       Q, K, Kb, Tg, states, incoming);
    hipLaunchKernelGGL(k_coal, dim3(BB * (NN / 16)), dim3(256), 0, stream,
                       PNb, incoming, outs);
    hipLaunchKernelGGL(k_mem, dim3(BB * NN / 16), dim3(512), 0, stream,
                       outs, Whb, bh, keys, pos, step, mem, epi, simo);
}